// Round 7
// baseline (393.122 us; speedup 1.0000x reference)
//
#include <hip/hip_runtime.h>
#include <math.h>

#define NK 512
#define DD 256
#define NB 32
#define NT 4096

typedef __attribute__((ext_vector_type(8))) _Float16 f16x8;
typedef __attribute__((ext_vector_type(4))) float f32x4;

#define MARGIN 1.5e-4f
#define DCH 16      // d per chunk
#define NCH 16      // chunks (DD/DCH)
#define ASTR 536    // LDS row stride in shorts (1072 B: 268 dw, 268%32=12 -> 2-way max)
#define PCAP   524288      // global pair capacity
#define PBCAP  2048        // per-block pair list capacity (LDS overlay)

__device__ __forceinline__ unsigned short f16bits(float x) {
    _Float16 h = (_Float16)x;           // v_cvt_f16_f32, RNE
    unsigned short s;
    __builtin_memcpy(&s, &h, 2);
    return s;
}

// ---------------------------------------------------------------------------
// Prep W: blocks 0..15 build Wpp (f16 w*4096, duplicated per-d slot pair);
// block 16 computes wsq (fp64 -> fp32 once) and zeroes counters.
// ---------------------------------------------------------------------------
__global__ __launch_bounds__(512) void prep_kernel(const float* __restrict__ W,
                                                   unsigned short* __restrict__ Wpp,
                                                   float* __restrict__ wsq,
                                                   int* __restrict__ gcnt,
                                                   int* __restrict__ pcnt,
                                                   int* __restrict__ oflow) {
    const int bx = blockIdx.x;
    const int k  = threadIdx.x;   // 0..511
    if (bx < NCH) {
        const int d0 = bx * DCH;
        float w[16];
        const float4* src4 = (const float4*)(W + (size_t)k * DD + d0);
        #pragma unroll
        for (int q = 0; q < 4; ++q) {
            float4 v = src4[q];
            w[4 * q + 0] = v.x; w[4 * q + 1] = v.y; w[4 * q + 2] = v.z; w[4 * q + 3] = v.w;
        }
        __align__(16) unsigned int dw[16];
        #pragma unroll
        for (int j = 0; j < 16; ++j) {
            unsigned short s = f16bits(w[j] * 4096.0f);  // exact pow2 scale, then RNE
            dw[j] = (unsigned int)s | ((unsigned int)s << 16);  // (wh, wh) slot pair
        }
        unsigned short* dst = Wpp + ((size_t)bx * 512 + k) * 32;
        #pragma unroll
        for (int j = 0; j < 4; ++j) ((int4*)dst)[j] = ((const int4*)dw)[j];
    } else {
        const float4* row = (const float4*)(W + (size_t)k * DD);
        double s = 0.0;
        #pragma unroll 8
        for (int i = 0; i < DD / 4; ++i) {
            float4 v = row[i];
            s += (double)v.x * v.x + (double)v.y * v.y + (double)v.z * v.z + (double)v.w * v.w;
        }
        wsq[k] = (float)s;
        if (k == 0) *gcnt = 0;
        if (k == 1) *pcnt = 0;
        if (k == 2) *oflow = 0;
    }
}

// ---------------------------------------------------------------------------
// Phase 1 (big tier): 32-token tiles for 3 independent blocks/CU.
// Block = 32 t x 512 codes, 256 thr / 4 waves; wave owns 32t x 128c ->
// acc[2][8] (64 AGPR). LDS 34.3 KB; __launch_bounds__(256,3) => 12 waves/CU
// = 3 blocks at independent phases (staging of one overlaps MFMA of others).
// Per-token numerics bit-identical to the validated kernel: staging threads
// 0..127 run the exact 64-load / 64-d fp64 chain / f16-split per thread;
// same ASTR pattern; same mt-outer nt-inner MFMA accumulation per chunk;
// same dist chain / top-2 / merge comparators. Light tie emit (R6 pattern).
// ---------------------------------------------------------------------------
__global__ __launch_bounds__(256, 3) void vq_phase1(const float* __restrict__ Z,
                                                    const unsigned short* __restrict__ Wpp,
                                                    const float* __restrict__ wsq,
                                                    int* __restrict__ out,
                                                    int* __restrict__ gties,
                                                    int* __restrict__ gcnt,
                                                    unsigned long long* __restrict__ slots,
                                                    int* __restrict__ gpairs,
                                                    int* __restrict__ pcnt,
                                                    int* __restrict__ oflow) {
    __shared__ __align__(16) short As[32 * ASTR];   // 34,304 B
    __shared__ int lcnt, gbase, pcl, pbase_sh;

    const int tid  = threadIdx.x;
    const int wave = tid >> 6;
    const int lane = tid & 63;
    const int lm   = lane & 15;
    const int lq   = lane >> 4;
    const int nw   = wave;        // k quarter (128 codes)

    const int bx = blockIdx.x;
    const int b  = bx >> 7;
    const int t0 = (bx & 127) * 32;

    const int t_l = tid & 31;
    const int dgs = (tid >> 5) & 3;   // staging segment for tid<128

    if (tid == 0) { lcnt = 0; pcl = 0; }

    // ---- staging: threads 0..127 (4 per token), exact 64-d fp64 chain
    double zacc = 0.0;
    if (tid < 128) {
        const float* zcol = Z + (size_t)b * DD * NT + t0 + t_l;
        #pragma unroll
        for (int g = 0; g < 8; ++g) {
            float zv[8];
            #pragma unroll
            for (int j = 0; j < 8; ++j)
                zv[j] = zcol[(size_t)(dgs * 64 + g * 8 + j) * NT];
            #pragma unroll
            for (int j = 0; j < 8; ++j)
                zacc = fma((double)zv[j], (double)zv[j], zacc);
            __align__(16) unsigned int u[8];
            #pragma unroll
            for (int j = 0; j < 8; ++j) {
                float z = zv[j];
                _Float16 zh = (_Float16)z;
                float rz = z - (float)zh;     // exact (Sterbenz)
                unsigned short hs, ls;
                __builtin_memcpy(&hs, &zh, 2);
                ls = f16bits(rz);
                u[j] = (unsigned int)hs | ((unsigned int)ls << 16);  // (zh, zl)
            }
            int4* dst = (int4*)&As[t_l * ASTR + dgs * 128 + g * 16];
            dst[0] = ((const int4*)u)[0];
            dst[1] = ((const int4*)u)[1];
        }
    }
    __syncthreads();   // staging visible; the ONLY pre-epilogue barrier

    // ---- B fragment base: lane reads 16 B of code (nw*128 + nt*16 + lm)
    const unsigned short* wb = Wpp + ((size_t)(nw * 128 + lm) * 32) + lq * 8;

    f32x4 acc[2][8];
    #pragma unroll
    for (int mt = 0; mt < 2; ++mt)
        #pragma unroll
        for (int nt = 0; nt < 8; ++nt)
            acc[mt][nt] = (f32x4){0.f, 0.f, 0.f, 0.f};

    #pragma unroll
    for (int c = 0; c < NCH; ++c) {
        // B loads for this chunk (TLP across 3 blocks hides L2 latency)
        int4 bv[8];
        const unsigned short* wp = wb + (size_t)c * 16384;
        #pragma unroll
        for (int nt = 0; nt < 8; ++nt)
            bv[nt] = *(const int4*)(wp + nt * 512);
        f16x8 a[2];
        #pragma unroll
        for (int mt = 0; mt < 2; ++mt)
            a[mt] = *(const f16x8*)&As[(mt * 16 + lm) * ASTR + c * 32 + lq * 8];
        #pragma unroll
        for (int mt = 0; mt < 2; ++mt)
            #pragma unroll
            for (int nt = 0; nt < 8; ++nt)
                acc[mt][nt] = __builtin_amdgcn_mfma_f32_16x16x32_f16(
                    a[mt], *(const f16x8*)&bv[nt], acc[mt][nt], 0, 0, 0);
    }

    // ---- epilogue. LDS overlay (As free after K-loop).
    __syncthreads();
    char* base = (char*)As;
    double* zred  = (double*)base;              // [4][32]  1024 B
    float*  zf    = (float*)(base + 1024);      // 32
    float*  qf    = (float*)(base + 1152);      // 32
    int*    tia   = (int*)(base + 1280);        // 32
    int*    ltok  = (int*)(base + 1408);        // 32
    float*  cb1   = (float*)(base + 1536);      // [32][4]
    float*  cb2   = (float*)(base + 2048);
    int*    cbi   = (int*)(base + 2560);
    int*    plist = (int*)(base + 3072);        // PBCAP ints (8 KB)

    if (tid < 128) zred[dgs * 32 + t_l] = zacc;
    __syncthreads();
    if (tid < 32) {
        double s = zred[tid];
        #pragma unroll
        for (int p = 1; p < 4; ++p) s += zred[p * 32 + tid];
        zf[tid] = (float)s;
    }
    __syncthreads();

    float wq[8];
    #pragma unroll
    for (int nt = 0; nt < 8; ++nt)
        wq[nt] = wsq[nw * 128 + nt * 16 + lm];
    const int kbase = nw * 128 + lm;

    #pragma unroll
    for (int mt = 0; mt < 2; ++mt) {
        #pragma unroll
        for (int r = 0; r < 4; ++r) {
            float zz = zf[mt * 16 + lq * 4 + r];
            float q1 = INFINITY, q2 = INFINITY;
            int i1 = 0x7fffffff;
            #pragma unroll
            for (int nt = 0; nt < 8; ++nt) {
                // acc holds cross*2^12; fl(2*cross) = acc * 2^-11 (exact pow2)
                float c2   = __fmul_rn(acc[mt][nt][r], 4.8828125e-4f);
                float dist = __fadd_rn(__fsub_rn(zz, c2), wq[nt]);
                int kk = kbase + nt * 16;
                if (dist < q1 || (dist == q1 && kk < i1)) { q2 = q1; q1 = dist; i1 = kk; }
                else if (dist < q2) q2 = dist;
            }
            #pragma unroll
            for (int mk = 1; mk <= 8; mk <<= 1) {
                float o1 = __shfl_xor(q1, mk);
                float o2 = __shfl_xor(q2, mk);
                int   oi = __shfl_xor(i1, mk);
                if (o1 < q1 || (o1 == q1 && oi < i1)) { q2 = fminf(q1, o2); q1 = o1; i1 = oi; }
                else { q2 = fminf(o1, q2); }
            }
            if (lm == 0) {
                int m = mt * 16 + lq * 4 + r;
                cb1[m * 4 + nw] = q1;
                cb2[m * 4 + nw] = q2;
                cbi[m * 4 + nw] = i1;
            }
        }
    }
    __syncthreads();
    if (tid < 32) {
        float q1 = cb1[tid * 4], q2 = cb2[tid * 4];
        int   i1 = cbi[tid * 4];
        #pragma unroll
        for (int p = 1; p < 4; ++p) {
            float c1 = cb1[tid * 4 + p], c2v = cb2[tid * 4 + p];
            int   ci = cbi[tid * 4 + p];
            if (c1 < q1 || (c1 == q1 && ci < i1)) { q2 = fminf(q1, c2v); q1 = c1; i1 = ci; }
            else { q2 = fminf(q2, c1); }
        }
        out[(size_t)b * NT + t0 + tid] = i1;
        qf[tid] = q1;
        int ta = -1;
        if (q2 - q1 <= MARGIN) {
            ta = atomicAdd(&lcnt, 1);
            ltok[ta] = tid;
        }
        tia[tid] = ta;
    }
    __syncthreads();           // merge done; lcnt/qf/tia final
    const int nloc = lcnt;
    if (nloc == 0) return;

    if (tid == 0) gbase = atomicAdd(gcnt, nloc);
    __syncthreads();

    if (tid < nloc) {
        gties[gbase + tid] = b * NT + t0 + ltok[tid];
        slots[gbase + tid] = 0xFFFFFFFFFFFFFFFFULL;
    }

    // ---- single-pass candidate emit: dists are live in registers
    #pragma unroll
    for (int mt = 0; mt < 2; ++mt) {
        #pragma unroll
        for (int r = 0; r < 4; ++r) {
            const int tok = mt * 16 + lq * 4 + r;
            const int ta  = tia[tok];
            if (ta < 0) continue;
            const int ti  = gbase + ta;
            const float thr = qf[tok] + MARGIN;
            const float zz  = zf[tok];
            #pragma unroll
            for (int nt = 0; nt < 8; ++nt) {
                float c2   = __fmul_rn(acc[mt][nt][r], 4.8828125e-4f);
                float dist = __fadd_rn(__fsub_rn(zz, c2), wq[nt]);
                if (dist <= thr) {
                    int p = atomicAdd(&pcl, 1);
                    if (p < PBCAP) plist[p] = (ti << 9) | (kbase + nt * 16);
                }
            }
        }
    }
    __syncthreads();
    if (tid == 0) {
        int take = pcl;
        int bs = atomicAdd(pcnt, take);
        pbase_sh = bs;
        if (take > PBCAP || bs + take > PCAP) *oflow = 1;
    }
    __syncthreads();
    {
        int take = pcl; if (take > PBCAP) take = PBCAP;
        for (int j = tid; j < take; j += 256) {
            int gp = pbase_sh + j;
            if (gp < PCAP) gpairs[gp] = plist[j];
        }
    }
}

// ---------------------------------------------------------------------------
// Pair fix (self-contained): one thread per (tie-token, candidate-code) pair.
// Streams Z[bb][d][t] once, computing BOTH the exact fp64 zsq chain (32
// seg-ordered partials, inner 8-fma chains — bit-identical to the validated
// full fix) and the exact fp32 fmaf cross chain (same ascending-d order).
// Winner per token via 64-bit atomicMin on (dist_bits<<32 | k) — dist > 0 so
// bit order = value order; ties pick smaller k (the validated comparator).
// ---------------------------------------------------------------------------
__global__ __launch_bounds__(256) void vq_fix_pairs(const float* __restrict__ Z,
                                                    const float* __restrict__ W,
                                                    const float* __restrict__ wsq,
                                                    const int* __restrict__ gties,
                                                    const int* __restrict__ gpairs,
                                                    const int* __restrict__ pcnt,
                                                    unsigned long long* __restrict__ slots) {
    int np = *pcnt;
    if (np > PCAP) np = PCAP;
    for (int j = blockIdx.x * 256 + threadIdx.x; j < np; j += (int)gridDim.x * 256) {
        const int p  = gpairs[j];
        const int ti = p >> 9;
        const int k  = p & 511;
        const int bt = gties[ti];
        const int bb = bt >> 12, t = bt & 4095;
        const float* zc = Z + (size_t)bb * DD * NT + t;
        const float4* wr = (const float4*)(W + (size_t)k * DD);

        double tot = 0.0;
        float a8 = 0.f;
        for (int seg = 0; seg < 32; ++seg) {
            float zv[8];
            #pragma unroll
            for (int jj = 0; jj < 8; ++jj)
                zv[jj] = zc[(size_t)(seg * 8 + jj) * NT];
            float4 w4a = wr[seg * 2];
            float4 w4b = wr[seg * 2 + 1];
            double s = 0.0;
            #pragma unroll
            for (int jj = 0; jj < 8; ++jj) {
                double zz = (double)zv[jj];
                s = fma(zz, zz, s);
            }
            tot += s;
            a8 = fmaf(zv[0], w4a.x, a8);
            a8 = fmaf(zv[1], w4a.y, a8);
            a8 = fmaf(zv[2], w4a.z, a8);
            a8 = fmaf(zv[3], w4a.w, a8);
            a8 = fmaf(zv[4], w4b.x, a8);
            a8 = fmaf(zv[5], w4b.y, a8);
            a8 = fmaf(zv[6], w4b.z, a8);
            a8 = fmaf(zv[7], w4b.w, a8);
        }
        float zqv = (float)tot;
        float da = __fadd_rn(__fsub_rn(zqv, __fmul_rn(2.0f, a8)), wsq[k]);
        unsigned long long key =
            ((unsigned long long)__float_as_uint(da) << 32) | (unsigned int)k;
        atomicMin(&slots[ti], key);
    }
}

// ---------------------------------------------------------------------------
// Final readout (skipped on overflow): out[bt] = winning k from slots.
// ---------------------------------------------------------------------------
__global__ __launch_bounds__(256) void vq_final(const int* __restrict__ gties,
                                                const int* __restrict__ gcnt,
                                                const int* __restrict__ oflow,
                                                const unsigned long long* __restrict__ slots,
                                                int* __restrict__ out) {
    if (*oflow) return;
    const int n = *gcnt;
    for (int j = blockIdx.x * 256 + threadIdx.x; j < n; j += (int)gridDim.x * 256) {
        out[gties[j]] = (int)(slots[j] & 511ULL);
    }
}

// ---------------------------------------------------------------------------
// Full tie fix (R2-validated). Big tier: runs only on overflow (oflow!=0).
// Tier-2: oflow == nullptr -> always runs.
// ---------------------------------------------------------------------------
__global__ __launch_bounds__(256) void vq_fix(const float* __restrict__ Z,
                                              const float* __restrict__ W,
                                              const float* __restrict__ wsq,
                                              const int* __restrict__ gties,
                                              const int* __restrict__ gcnt,
                                              int* __restrict__ out,
                                              const int* __restrict__ oflow) {
    if (oflow != nullptr && *oflow == 0) return;

    __shared__ __align__(16) float Zs[8][256];
    __shared__ double pz[8][32];
    __shared__ float  zsqs[8];
    __shared__ int    bts[8];
    __shared__ float  rv[8][4];
    __shared__ int    ri[8][4];

    const int tid  = threadIdx.x;
    const int lane = tid & 63;
    const int wvx  = tid >> 6;
    const int n    = *gcnt;

    for (int base = blockIdx.x * 8; base < n; base += (int)gridDim.x * 8) {
        const int m = (n - base < 8) ? (n - base) : 8;
        __syncthreads();
        if (tid < 8) bts[tid] = gties[base + ((tid < m) ? tid : 0)];
        __syncthreads();

        #pragma unroll
        for (int i = 0; i < 8; ++i) {
            if (i < m) {
                int tb = bts[i];
                int bb = tb >> 12, t = tb & 4095;
                Zs[i][tid] = Z[(size_t)bb * DD * NT + (size_t)tid * NT + t];
            }
        }
        __syncthreads();

        {
            int i = tid >> 5, seg = tid & 31;
            double s = 0.0;
            #pragma unroll
            for (int j = 0; j < 8; ++j) {
                double zz = (double)Zs[i][seg * 8 + j];
                s = fma(zz, zz, s);
            }
            pz[i][seg] = s;
        }
        __syncthreads();
        if (tid < 8) {
            double s = 0.0;
            #pragma unroll
            for (int j = 0; j < 32; ++j) s += pz[tid][j];
            zsqs[tid] = (float)s;
        }
        __syncthreads();

        float da[2][8];
        #pragma unroll
        for (int rr = 0; rr < 2; ++rr) {
            int k = tid + rr * 256;
            const float4* wr = (const float4*)(W + (size_t)k * DD);
            float a8[8];
            #pragma unroll
            for (int i = 0; i < 8; ++i) a8[i] = 0.f;
            #pragma unroll 2
            for (int q = 0; q < 64; ++q) {
                float4 w4 = wr[q];
                #pragma unroll
                for (int i = 0; i < 8; ++i) {
                    float4 z4 = *(const float4*)&Zs[i][4 * q];   // LDS broadcast
                    a8[i] = fmaf(z4.x, w4.x, a8[i]);
                    a8[i] = fmaf(z4.y, w4.y, a8[i]);
                    a8[i] = fmaf(z4.z, w4.z, a8[i]);
                    a8[i] = fmaf(z4.w, w4.w, a8[i]);
                }
            }
            float wqv = wsq[k];
            #pragma unroll
            for (int i = 0; i < 8; ++i)
                da[rr][i] = __fadd_rn(__fsub_rn(zsqs[i], __fmul_rn(2.0f, a8[i])), wqv);
        }

        #pragma unroll
        for (int i = 0; i < 8; ++i) {
            float v = da[0][i]; int ix = tid;
            if (da[1][i] < v) { v = da[1][i]; ix = tid + 256; }
            #pragma unroll
            for (int mk = 1; mk <= 32; mk <<= 1) {
                float ov = __shfl_xor(v, mk);
                int   oi = __shfl_xor(ix, mk);
                if (ov < v || (ov == v && oi < ix)) { v = ov; ix = oi; }
            }
            if (lane == 0) { rv[i][wvx] = v; ri[i][wvx] = ix; }
        }
        __syncthreads();
        if (tid < 8 && tid < m) {
            float v = INFINITY; int ix = 0x7fffffff;
            #pragma unroll
            for (int w = 0; w < 4; ++w) {
                if (rv[tid][w] < v || (rv[tid][w] == v && ri[tid][w] < ix)) {
                    v = rv[tid][w]; ix = ri[tid][w];
                }
            }
            out[bts[tid]] = ix;
        }
    }
}

// ---------------------------------------------------------------------------
// Phase 1 (tier-2, R2-validated): 4-wave, in-kernel staging.
// ---------------------------------------------------------------------------
__global__ __launch_bounds__(256, 2) void vq_phase1_reg(const float* __restrict__ Z,
                                                        const unsigned short* __restrict__ Wpp,
                                                        const float* __restrict__ wsq,
                                                        int* __restrict__ out,
                                                        int* __restrict__ gties,
                                                        int* __restrict__ gcnt) {
    __shared__ __align__(16) short As[64 * ASTR];
    __shared__ int lcnt, gbase;

    const int tid  = threadIdx.x;
    const int wave = tid >> 6;
    const int lane = tid & 63;
    const int lm   = lane & 15;
    const int lq   = lane >> 4;
    const int nw   = wave;

    const int bx = blockIdx.x;
    const int b  = bx >> 6;
    const int t0 = (bx & 63) * 64;

    const int t_l = tid & 63;
    const int dgs = tid >> 6;

    const float* zcol = Z + (size_t)b * DD * NT + t0 + t_l;

    if (tid == 0) lcnt = 0;

    double zacc = 0.0;
    #pragma unroll
    for (int half = 0; half < 2; ++half) {
        float zv[32];
        #pragma unroll
        for (int j = 0; j < 32; ++j)
            zv[j] = zcol[(size_t)(dgs * 64 + half * 32 + j) * NT];
        #pragma unroll
        for (int j = 0; j < 32; ++j)
            zacc = fma((double)zv[j], (double)zv[j], zacc);
        #pragma unroll
        for (int j0 = 0; j0 < 32; j0 += 4) {
            __align__(16) unsigned int u[4];
            #pragma unroll
            for (int q = 0; q < 4; ++q) {
                float z = zv[j0 + q];
                _Float16 zh = (_Float16)z;
                float rz = z - (float)zh;
                unsigned short hs, ls;
                __builtin_memcpy(&hs, &zh, 2);
                ls = f16bits(rz);
                u[q] = (unsigned int)hs | ((unsigned int)ls << 16);
            }
            *(int4*)&As[t_l * ASTR + (dgs * 64 + half * 32 + j0) * 2] = *(const int4*)u;
        }
    }
    __syncthreads();

    const unsigned short* wb = Wpp + ((size_t)(nw * 128 + lm) * 32) + lq * 8;

    f32x4 acc[4][8];
    #pragma unroll
    for (int mt = 0; mt < 4; ++mt)
        #pragma unroll
        for (int nt = 0; nt < 8; ++nt)
            acc[mt][nt] = (f32x4){0.f, 0.f, 0.f, 0.f};

    int4 bv0[8], bv1[8];
    #pragma unroll
    for (int nt = 0; nt < 8; ++nt)
        bv0[nt] = *(const int4*)(wb + nt * 512);

    #pragma unroll
    for (int c = 0; c < NCH; ++c) {
        int4* cur = (c & 1) ? bv1 : bv0;
        int4* nxt = (c & 1) ? bv0 : bv1;
        if (c < NCH - 1) {
            const unsigned short* wp = wb + (size_t)(c + 1) * 16384;
            #pragma unroll
            for (int nt = 0; nt < 8; ++nt)
                nxt[nt] = *(const int4*)(wp + nt * 512);
        }
        f16x8 a[4];
        #pragma unroll
        for (int mt = 0; mt < 4; ++mt)
            a[mt] = *(const f16x8*)&As[(mt * 16 + lm) * ASTR + c * 32 + lq * 8];
        #pragma unroll
        for (int mt = 0; mt < 4; ++mt)
            #pragma unroll
            for (int nt = 0; nt < 8; ++nt)
                acc[mt][nt] = __builtin_amdgcn_mfma_f32_16x16x32_f16(
                    a[mt], *(const f16x8*)&cur[nt], acc[mt][nt], 0, 0, 0);
    }

    __syncthreads();
    double* zred = (double*)As;
    float*  zf   = (float*)(As + 1024);
    float*  cb1  = (float*)(As + 1536);
    float*  cb2  = (float*)(As + 2048);
    int*    cbi  = (int*)(As + 2560);
    int*    llist = (int*)(As + 3072);

    zred[dgs * 64 + t_l] = zacc;
    __syncthreads();
    if (tid < 64) {
        double s = zred[tid];
        #pragma unroll
        for (int p = 1; p < 4; ++p) s += zred[p * 64 + tid];
        zf[tid] = (float)s;
    }
    __syncthreads();

    float wq[8];
    #pragma unroll
    for (int nt = 0; nt < 8; ++nt)
        wq[nt] = wsq[nw * 128 + nt * 16 + lm];
    const int kbase = nw * 128 + lm;

    #pragma unroll
    for (int mt = 0; mt < 4; ++mt) {
        #pragma unroll
        for (int r = 0; r < 4; ++r) {
            float zz = zf[mt * 16 + lq * 4 + r];
            float q1 = INFINITY, q2 = INFINITY;
            int i1 = 0x7fffffff;
            #pragma unroll
            for (int nt = 0; nt < 8; ++nt) {
                float c2   = __fmul_rn(acc[mt][nt][r], 4.8828125e-4f);
                float dist = __fadd_rn(__fsub_rn(zz, c2), wq[nt]);
                int kk = kbase + nt * 16;
                if (dist < q1 || (dist == q1 && kk < i1)) { q2 = q1; q1 = dist; i1 = kk; }
                else if (dist < q2) q2 = dist;
            }
            #pragma unroll
            for (int mk = 1; mk <= 8; mk <<= 1) {
                float o1 = __shfl_xor(q1, mk);
                float o2 = __shfl_xor(q2, mk);
                int   oi = __shfl_xor(i1, mk);
                if (o1 < q1 || (o1 == q1 && oi < i1)) { q2 = fminf(q1, o2); q1 = o1; i1 = oi; }
                else { q2 = fminf(o1, q2); }
            }
            if (lm == 0) {
                int m = mt * 16 + lq * 4 + r;
                cb1[m * 4 + nw] = q1;
                cb2[m * 4 + nw] = q2;
                cbi[m * 4 + nw] = i1;
            }
        }
    }
    __syncthreads();
    if (tid < 64) {
        float q1 = cb1[tid * 4], q2 = cb2[tid * 4];
        int   i1 = cbi[tid * 4];
        #pragma unroll
        for (int p = 1; p < 4; ++p) {
            float c1 = cb1[tid * 4 + p], c2v = cb2[tid * 4 + p];
            int   ci = cbi[tid * 4 + p];
            if (c1 < q1 || (c1 == q1 && ci < i1)) { q2 = fminf(q1, c2v); q1 = c1; i1 = ci; }
            else { q2 = fminf(q2, c1); }
        }
        out[(size_t)b * NT + t0 + tid] = i1;
        if (q2 - q1 <= MARGIN) {
            int p = atomicAdd(&lcnt, 1);
            llist[p] = b * NT + t0 + tid;
        }
    }
    __syncthreads();
    if (tid == 0) gbase = (lcnt > 0) ? atomicAdd(gcnt, lcnt) : 0;
    __syncthreads();
    if (tid < lcnt) gties[gbase + tid] = llist[tid];
}

// ---------------------------------------------------------------------------
// Fallback (R1 kernel) if ws is too small.
// ---------------------------------------------------------------------------
#define BT 128
#define BK 128
#define DCHUNK 32
#define NKC (NK / BK)
#define NDC (DD / DCHUNK)
#define WSTR (BK + 4)

__global__ __launch_bounds__(256) void vq_fallback(const float* __restrict__ Z,
                                                   const float* __restrict__ W,
                                                   int* __restrict__ out) {
    __shared__ __align__(16) float Zs[DCHUNK * BT];
    __shared__ __align__(16) float Ws[DCHUNK * WSTR];
    __shared__ float wsqs[NK];

    const int tid = threadIdx.x;
    const int tx  = tid & 15;
    const int ty  = tid >> 4;
    const int b   = blockIdx.y;
    const int t0  = blockIdx.x * BT;

    for (int k = tid; k < NK; k += 256) {
        const float4* row = (const float4*)(W + (size_t)k * DD);
        double s = 0.0;
        for (int i = 0; i < DD / 4; ++i) {
            float4 v = row[i];
            s += (double)v.x * v.x + (double)v.y * v.y + (double)v.z * v.z + (double)v.w * v.w;
        }
        wsqs[k] = (float)s;
    }

    const float* Zb = Z + (size_t)b * DD * NT + t0;

    float best[8]; int bidx[8];
    #pragma unroll
    for (int a = 0; a < 8; ++a) { best[a] = INFINITY; bidx[a] = 0x7fffffff; }
    double zsqd[8];
    #pragma unroll
    for (int a = 0; a < 8; ++a) zsqd[a] = 0.0;
    float zsqf[8];

    for (int kc = 0; kc < NKC; ++kc) {
        float acc[8][8];
        #pragma unroll
        for (int a = 0; a < 8; ++a)
            #pragma unroll
            for (int c = 0; c < 8; ++c) acc[a][c] = 0.f;

        for (int dc = 0; dc < NDC; ++dc) {
            const int d0 = dc * DCHUNK;
            __syncthreads();
            #pragma unroll
            for (int i = 0; i < 4; ++i) {
                int f  = tid + i * 256;
                int r  = f >> 5;
                int c4 = f & 31;
                float4 v = *(const float4*)(Zb + (size_t)(d0 + r) * NT + c4 * 4);
                *(float4*)(&Zs[r * BT + c4 * 4]) = v;
            }
            #pragma unroll
            for (int i = 0; i < 4; ++i) {
                int u  = tid + i * 256;
                int k  = u >> 3;
                int rg = u & 7;
                float4 v = *(const float4*)(W + (size_t)(kc * BK + k) * DD + d0 + rg * 4);
                Ws[(rg * 4 + 0) * WSTR + k] = v.x;
                Ws[(rg * 4 + 1) * WSTR + k] = v.y;
                Ws[(rg * 4 + 2) * WSTR + k] = v.z;
                Ws[(rg * 4 + 3) * WSTR + k] = v.w;
            }
            __syncthreads();
            #pragma unroll 4
            for (int d = 0; d < DCHUNK; ++d) {
                float4 z0 = *(const float4*)(&Zs[d * BT + ty * 8]);
                float4 z1 = *(const float4*)(&Zs[d * BT + ty * 8 + 4]);
                float4 w0 = *(const float4*)(&Ws[d * WSTR + tx * 8]);
                float4 w1 = *(const float4*)(&Ws[d * WSTR + tx * 8 + 4]);
                float za[8] = {z0.x, z0.y, z0.z, z0.w, z1.x, z1.y, z1.z, z1.w};
                float wa[8] = {w0.x, w0.y, w0.z, w0.w, w1.x, w1.y, w1.z, w1.w};
                if (kc == 0) {
                    #pragma unroll
                    for (int a = 0; a < 8; ++a)
                        zsqd[a] = fma((double)za[a], (double)za[a], zsqd[a]);
                }
                #pragma unroll
                for (int a = 0; a < 8; ++a)
                    #pragma unroll
                    for (int c = 0; c < 8; ++c)
                        acc[a][c] = fmaf(za[a], wa[c], acc[a][c]);
            }
        }
        if (kc == 0) {
            #pragma unroll
            for (int a = 0; a < 8; ++a) zsqf[a] = (float)zsqd[a];
        }
        #pragma unroll
        for (int c = 0; c < 8; ++c) {
            int   kg = kc * BK + tx * 8 + c;
            float wqv = wsqs[kg];
            #pragma unroll
            for (int a = 0; a < 8; ++a) {
                float c2   = __fmul_rn(2.0f, acc[a][c]);
                float s    = __fsub_rn(zsqf[a], c2);
                float dist = __fadd_rn(s, wqv);
                if (dist < best[a] || (dist == best[a] && kg < bidx[a])) {
                    best[a] = dist; bidx[a] = kg;
                }
            }
        }
    }
    __syncthreads();
    float* redv = Zs;
    int*   redi = (int*)Ws;
    #pragma unroll
    for (int a = 0; a < 8; ++a) {
        int tl2 = ty * 8 + a;
        redv[tl2 * 16 + tx] = best[a];
        redi[tl2 * 16 + tx] = bidx[a];
    }
    __syncthreads();
    if (tid < BT) {
        float bv = INFINITY; int bi = 0x7fffffff;
        #pragma unroll
        for (int j = 0; j < 16; ++j) {
            float v = redv[tid * 16 + j];
            int   i = redi[tid * 16 + j];
            if (v < bv || (v == bv && i < bi)) { bv = v; bi = i; }
        }
        out[(size_t)b * NT + t0 + tid] = bi;
    }
}

extern "C" void kernel_launch(void* const* d_in, const int* in_sizes, int n_in,
                              void* d_out, int out_size, void* d_ws, size_t ws_size,
                              hipStream_t stream) {
    const float* Z = (const float*)d_in[0];   // [B, D, T]
    const float* W = (const float*)d_in[1];   // [K, D]
    int* out = (int*)d_out;                   // [B, T]

    // ---- tier-big layout (~5.8 MB)
    const size_t OFF_WSQ  = 0;                         // 512 f32
    const size_t OFF_CNT  = 2048;                      // gcnt
    const size_t OFF_PCNT = 2052;                      // pcnt
    const size_t OFF_OFL  = 2056;                      // oflow
    const size_t OFF_WPP  = 4096;                      // 512 KB
    const size_t OFF_TIE  = OFF_WPP + 524288;          // 131072 ints (512 KB)
    const size_t OFF_SLOT = OFF_TIE + 524288;          // 131072 u64 (1 MB)
    const size_t OFF_PAIR = OFF_SLOT + 1048576;        // PCAP ints (2 MB)
    const size_t NEED_BIG = OFF_PAIR + (size_t)PCAP * 4;

    // ---- tier-2 layout (R2 path)
    const size_t T2_WSQ = 0;
    const size_t T2_CNT = 2048;
    const size_t T2_WPP = 4096;
    const size_t T2_TIE = T2_WPP + 524288;
    const size_t NEED_T2 = T2_TIE + 524288;

    if (ws_size >= NEED_BIG) {
        float* wsq  = (float*)((char*)d_ws + OFF_WSQ);
        int*   gcnt = (int*)((char*)d_ws + OFF_CNT);
        int*   pcnt = (int*)((char*)d_ws + OFF_PCNT);
        int*   ofl  = (int*)((char*)d_ws + OFF_OFL);
        unsigned short* wpp = (unsigned short*)((char*)d_ws + OFF_WPP);
        int*   gties = (int*)((char*)d_ws + OFF_TIE);
        unsigned long long* slots = (unsigned long long*)((char*)d_ws + OFF_SLOT);
        int*   gpairs = (int*)((char*)d_ws + OFF_PAIR);

        prep_kernel<<<dim3(NCH + 1), dim3(512), 0, stream>>>(W, wpp, wsq, gcnt, pcnt, ofl);
        vq_phase1<<<dim3(4096), dim3(256), 0, stream>>>(Z, wpp, wsq, out, gties, gcnt,
                                                        slots, gpairs, pcnt, ofl);
        vq_fix_pairs<<<dim3(256), dim3(256), 0, stream>>>(Z, W, wsq, gties, gpairs, pcnt, slots);
        vq_fix<<<dim3(256), dim3(256), 0, stream>>>(Z, W, wsq, gties, gcnt, out, ofl);
        vq_final<<<dim3(256), dim3(256), 0, stream>>>(gties, gcnt, ofl, slots, out);
    } else if (ws_size >= NEED_T2) {
        float* wsq  = (float*)((char*)d_ws + T2_WSQ);
        int*   gcnt = (int*)((char*)d_ws + T2_CNT);
        unsigned short* wpp = (unsigned short*)((char*)d_ws + T2_WPP);
        int*   gties = (int*)((char*)d_ws + T2_TIE);

        prep_kernel<<<dim3(NCH + 1), dim3(512), 0, stream>>>(W, wpp, wsq, gcnt, gcnt, gcnt);
        vq_phase1_reg<<<dim3(2048), dim3(256), 0, stream>>>(Z, wpp, wsq, out, gties, gcnt);
        vq_fix<<<dim3(256), dim3(256), 0, stream>>>(Z, W, wsq, gties, gcnt, out, nullptr);
    } else {
        vq_fallback<<<dim3(NT / BT, NB), dim3(256), 0, stream>>>(Z, W, out);
    }
}

// Round 8
// 359.807 us; speedup vs baseline: 1.0926x; 1.0926x over previous
//
#include <hip/hip_runtime.h>
#include <math.h>

#define NK 512
#define DD 256
#define NB 32
#define NT 4096

typedef __attribute__((ext_vector_type(8))) _Float16 f16x8;
typedef __attribute__((ext_vector_type(4))) float f32x4;

#define MARGIN 1.5e-4f
#define DCH 16      // d per chunk
#define NCH 16      // chunks (DD/DCH)
#define ASTR 536    // LDS row stride in shorts (1072 B: 268 dw, 268%32=12 -> 2-way max)
#define PCAP   524288      // global pair capacity
#define PBCAP  2048        // per-block pair list capacity (LDS overlay)

__device__ __forceinline__ unsigned short f16bits(float x) {
    _Float16 h = (_Float16)x;           // v_cvt_f16_f32, RNE
    unsigned short s;
    __builtin_memcpy(&s, &h, 2);
    return s;
}

// ---------------------------------------------------------------------------
// Prep W: blocks 0..15 build Wpp (f16 w*4096, duplicated per-d slot pair);
// block 16 computes wsq (fp64 -> fp32 once) and zeroes counters.
// ---------------------------------------------------------------------------
__global__ __launch_bounds__(512) void prep_kernel(const float* __restrict__ W,
                                                   unsigned short* __restrict__ Wpp,
                                                   float* __restrict__ wsq,
                                                   int* __restrict__ gcnt,
                                                   int* __restrict__ pcnt,
                                                   int* __restrict__ oflow) {
    const int bx = blockIdx.x;
    const int k  = threadIdx.x;   // 0..511
    if (bx < NCH) {
        const int d0 = bx * DCH;
        float w[16];
        const float4* src4 = (const float4*)(W + (size_t)k * DD + d0);
        #pragma unroll
        for (int q = 0; q < 4; ++q) {
            float4 v = src4[q];
            w[4 * q + 0] = v.x; w[4 * q + 1] = v.y; w[4 * q + 2] = v.z; w[4 * q + 3] = v.w;
        }
        __align__(16) unsigned int dw[16];
        #pragma unroll
        for (int j = 0; j < 16; ++j) {
            unsigned short s = f16bits(w[j] * 4096.0f);  // exact pow2 scale, then RNE
            dw[j] = (unsigned int)s | ((unsigned int)s << 16);  // (wh, wh) slot pair
        }
        unsigned short* dst = Wpp + ((size_t)bx * 512 + k) * 32;
        #pragma unroll
        for (int j = 0; j < 4; ++j) ((int4*)dst)[j] = ((const int4*)dw)[j];
    } else {
        const float4* row = (const float4*)(W + (size_t)k * DD);
        double s = 0.0;
        #pragma unroll 8
        for (int i = 0; i < DD / 4; ++i) {
            float4 v = row[i];
            s += (double)v.x * v.x + (double)v.y * v.y + (double)v.z * v.z + (double)v.w * v.w;
        }
        wsq[k] = (float)s;
        if (k == 0) *gcnt = 0;
        if (k == 1) *pcnt = 0;
        if (k == 2) *oflow = 0;
    }
}

// ---------------------------------------------------------------------------
// Phase 1 (big tier) = the R2-measured-best structure (160 us): block =
// 64 t x 512 codes, 256 thr / 4 waves, wave owns 64t x 128c -> acc[4][8]
// (max B-amortization: 32 MFMA per chunk per wave). In-kernel staging with
// the exact validated chains; barrier-free K-loop, B depth-1 named double
// buffer from L2. Epilogue: R6 light tie emit (qf/tia/ltok + single-pass
// in-register candidate emit). All approx-path numerics bit-identical to
// the validated kernel.
// ---------------------------------------------------------------------------
__global__ __launch_bounds__(256, 2) void vq_phase1(const float* __restrict__ Z,
                                                    const unsigned short* __restrict__ Wpp,
                                                    const float* __restrict__ wsq,
                                                    int* __restrict__ out,
                                                    int* __restrict__ gties,
                                                    int* __restrict__ gcnt,
                                                    unsigned long long* __restrict__ slots,
                                                    int* __restrict__ gpairs,
                                                    int* __restrict__ pcnt,
                                                    int* __restrict__ oflow) {
    __shared__ __align__(16) short As[64 * ASTR];   // 68,608 B
    __shared__ int lcnt, gbase, pcl, pbase_sh;

    const int tid  = threadIdx.x;
    const int wave = tid >> 6;
    const int lane = tid & 63;
    const int lm   = lane & 15;
    const int lq   = lane >> 4;
    const int nw   = wave;        // k quarter (128 codes)

    const int bx = blockIdx.x;
    const int b  = bx >> 6;
    const int t0 = (bx & 63) * 64;

    const int t_l = tid & 63;
    const int dgs = tid >> 6;     // 0..3, 64 d each

    const float* zcol = Z + (size_t)b * DD * NT + t0 + t_l;

    if (tid == 0) { lcnt = 0; pcl = 0; }

    // ---- staging: exact validated per-thread chain (64 loads, fp64, split)
    double zacc = 0.0;
    #pragma unroll
    for (int half = 0; half < 2; ++half) {
        float zv[32];
        #pragma unroll
        for (int j = 0; j < 32; ++j)
            zv[j] = zcol[(size_t)(dgs * 64 + half * 32 + j) * NT];
        #pragma unroll
        for (int j = 0; j < 32; ++j)
            zacc = fma((double)zv[j], (double)zv[j], zacc);
        #pragma unroll
        for (int j0 = 0; j0 < 32; j0 += 4) {
            __align__(16) unsigned int u[4];
            #pragma unroll
            for (int q = 0; q < 4; ++q) {
                float z = zv[j0 + q];
                _Float16 zh = (_Float16)z;
                float rz = z - (float)zh;     // exact (Sterbenz)
                unsigned short hs, ls;
                __builtin_memcpy(&hs, &zh, 2);
                ls = f16bits(rz);
                u[q] = (unsigned int)hs | ((unsigned int)ls << 16);  // (zh, zl)
            }
            *(int4*)&As[t_l * ASTR + (dgs * 64 + half * 32 + j0) * 2] = *(const int4*)u;
        }
    }
    __syncthreads();   // staging visible; the ONLY pre-epilogue barrier

    const unsigned short* wb = Wpp + ((size_t)(nw * 128 + lm) * 32) + lq * 8;

    f32x4 acc[4][8];
    #pragma unroll
    for (int mt = 0; mt < 4; ++mt)
        #pragma unroll
        for (int nt = 0; nt < 8; ++nt)
            acc[mt][nt] = (f32x4){0.f, 0.f, 0.f, 0.f};

    int4 bv0[8], bv1[8];
    #pragma unroll
    for (int nt = 0; nt < 8; ++nt)
        bv0[nt] = *(const int4*)(wb + nt * 512);

    #pragma unroll
    for (int c = 0; c < NCH; ++c) {
        int4* cur = (c & 1) ? bv1 : bv0;
        int4* nxt = (c & 1) ? bv0 : bv1;
        if (c < NCH - 1) {
            const unsigned short* wp = wb + (size_t)(c + 1) * 16384;
            #pragma unroll
            for (int nt = 0; nt < 8; ++nt)
                nxt[nt] = *(const int4*)(wp + nt * 512);
        }
        f16x8 a[4];
        #pragma unroll
        for (int mt = 0; mt < 4; ++mt)
            a[mt] = *(const f16x8*)&As[(mt * 16 + lm) * ASTR + c * 32 + lq * 8];
        #pragma unroll
        for (int mt = 0; mt < 4; ++mt)
            #pragma unroll
            for (int nt = 0; nt < 8; ++nt)
                acc[mt][nt] = __builtin_amdgcn_mfma_f32_16x16x32_f16(
                    a[mt], *(const f16x8*)&cur[nt], acc[mt][nt], 0, 0, 0);
    }

    // ---- epilogue. LDS overlay (As free after K-loop).
    __syncthreads();
    char* base = (char*)As;
    double* zred  = (double*)base;              // [4][64]  2048 B
    float*  zf    = (float*)(base + 2048);      // 64
    float*  qf    = (float*)(base + 2304);      // 64
    int*    tia   = (int*)(base + 2560);        // 64
    int*    ltok  = (int*)(base + 2816);        // 64
    float*  cb1   = (float*)(base + 3072);      // [64][4]
    float*  cb2   = (float*)(base + 4096);
    int*    cbi   = (int*)(base + 5120);
    int*    plist = (int*)(base + 6144);        // PBCAP ints (8 KB)

    zred[dgs * 64 + t_l] = zacc;
    __syncthreads();
    if (tid < 64) {
        double s = zred[tid];
        #pragma unroll
        for (int p = 1; p < 4; ++p) s += zred[p * 64 + tid];
        zf[tid] = (float)s;
    }
    __syncthreads();

    float wq[8];
    #pragma unroll
    for (int nt = 0; nt < 8; ++nt)
        wq[nt] = wsq[nw * 128 + nt * 16 + lm];
    const int kbase = nw * 128 + lm;

    #pragma unroll
    for (int mt = 0; mt < 4; ++mt) {
        #pragma unroll
        for (int r = 0; r < 4; ++r) {
            float zz = zf[mt * 16 + lq * 4 + r];
            float q1 = INFINITY, q2 = INFINITY;
            int i1 = 0x7fffffff;
            #pragma unroll
            for (int nt = 0; nt < 8; ++nt) {
                // acc holds cross*2^12; fl(2*cross) = acc * 2^-11 (exact pow2)
                float c2   = __fmul_rn(acc[mt][nt][r], 4.8828125e-4f);
                float dist = __fadd_rn(__fsub_rn(zz, c2), wq[nt]);
                int kk = kbase + nt * 16;
                if (dist < q1 || (dist == q1 && kk < i1)) { q2 = q1; q1 = dist; i1 = kk; }
                else if (dist < q2) q2 = dist;
            }
            #pragma unroll
            for (int mk = 1; mk <= 8; mk <<= 1) {
                float o1 = __shfl_xor(q1, mk);
                float o2 = __shfl_xor(q2, mk);
                int   oi = __shfl_xor(i1, mk);
                if (o1 < q1 || (o1 == q1 && oi < i1)) { q2 = fminf(q1, o2); q1 = o1; i1 = oi; }
                else { q2 = fminf(o1, q2); }
            }
            if (lm == 0) {
                int m = mt * 16 + lq * 4 + r;
                cb1[m * 4 + nw] = q1;
                cb2[m * 4 + nw] = q2;
                cbi[m * 4 + nw] = i1;
            }
        }
    }
    __syncthreads();
    if (tid < 64) {
        float q1 = cb1[tid * 4], q2 = cb2[tid * 4];
        int   i1 = cbi[tid * 4];
        #pragma unroll
        for (int p = 1; p < 4; ++p) {
            float c1 = cb1[tid * 4 + p], c2v = cb2[tid * 4 + p];
            int   ci = cbi[tid * 4 + p];
            if (c1 < q1 || (c1 == q1 && ci < i1)) { q2 = fminf(q1, c2v); q1 = c1; i1 = ci; }
            else { q2 = fminf(q2, c1); }
        }
        out[(size_t)b * NT + t0 + tid] = i1;
        qf[tid] = q1;
        int ta = -1;
        if (q2 - q1 <= MARGIN) {
            ta = atomicAdd(&lcnt, 1);
            ltok[ta] = tid;
        }
        tia[tid] = ta;
    }
    __syncthreads();           // merge done; lcnt/qf/tia final
    const int nloc = lcnt;
    if (nloc == 0) return;

    if (tid == 0) gbase = atomicAdd(gcnt, nloc);
    __syncthreads();

    if (tid < nloc) {
        gties[gbase + tid] = b * NT + t0 + ltok[tid];
        slots[gbase + tid] = 0xFFFFFFFFFFFFFFFFULL;
    }

    // ---- single-pass candidate emit: dists are live in registers
    #pragma unroll
    for (int mt = 0; mt < 4; ++mt) {
        #pragma unroll
        for (int r = 0; r < 4; ++r) {
            const int tok = mt * 16 + lq * 4 + r;
            const int ta  = tia[tok];
            if (ta < 0) continue;
            const int ti  = gbase + ta;
            const float thr = qf[tok] + MARGIN;
            const float zz  = zf[tok];
            #pragma unroll
            for (int nt = 0; nt < 8; ++nt) {
                float c2   = __fmul_rn(acc[mt][nt][r], 4.8828125e-4f);
                float dist = __fadd_rn(__fsub_rn(zz, c2), wq[nt]);
                if (dist <= thr) {
                    int p = atomicAdd(&pcl, 1);
                    if (p < PBCAP) plist[p] = (ti << 9) | (kbase + nt * 16);
                }
            }
        }
    }
    __syncthreads();
    if (tid == 0) {
        int take = pcl;
        int bs = atomicAdd(pcnt, take);
        pbase_sh = bs;
        if (take > PBCAP || bs + take > PCAP) *oflow = 1;
    }
    __syncthreads();
    {
        int take = pcl; if (take > PBCAP) take = PBCAP;
        for (int j = tid; j < take; j += 256) {
            int gp = pbase_sh + j;
            if (gp < PCAP) gpairs[gp] = plist[j];
        }
    }
}

// ---------------------------------------------------------------------------
// Pair fix (self-contained, R6-validated): one thread per pair; streams the
// Z column once computing BOTH the exact fp64 zsq chain (32 seg-ordered
// partials, inner 8-fma chains) and the exact fp32 fmaf cross chain (same
// ascending-d order). Winner per token via 64-bit atomicMin on
// (dist_bits<<32 | k) — the validated comparator.
// ---------------------------------------------------------------------------
__global__ __launch_bounds__(256) void vq_fix_pairs(const float* __restrict__ Z,
                                                    const float* __restrict__ W,
                                                    const float* __restrict__ wsq,
                                                    const int* __restrict__ gties,
                                                    const int* __restrict__ gpairs,
                                                    const int* __restrict__ pcnt,
                                                    unsigned long long* __restrict__ slots) {
    int np = *pcnt;
    if (np > PCAP) np = PCAP;
    for (int j = blockIdx.x * 256 + threadIdx.x; j < np; j += (int)gridDim.x * 256) {
        const int p  = gpairs[j];
        const int ti = p >> 9;
        const int k  = p & 511;
        const int bt = gties[ti];
        const int bb = bt >> 12, t = bt & 4095;
        const float* zc = Z + (size_t)bb * DD * NT + t;
        const float4* wr = (const float4*)(W + (size_t)k * DD);

        double tot = 0.0;
        float a8 = 0.f;
        for (int seg = 0; seg < 32; ++seg) {
            float zv[8];
            #pragma unroll
            for (int jj = 0; jj < 8; ++jj)
                zv[jj] = zc[(size_t)(seg * 8 + jj) * NT];
            float4 w4a = wr[seg * 2];
            float4 w4b = wr[seg * 2 + 1];
            double s = 0.0;
            #pragma unroll
            for (int jj = 0; jj < 8; ++jj) {
                double zz = (double)zv[jj];
                s = fma(zz, zz, s);
            }
            tot += s;
            a8 = fmaf(zv[0], w4a.x, a8);
            a8 = fmaf(zv[1], w4a.y, a8);
            a8 = fmaf(zv[2], w4a.z, a8);
            a8 = fmaf(zv[3], w4a.w, a8);
            a8 = fmaf(zv[4], w4b.x, a8);
            a8 = fmaf(zv[5], w4b.y, a8);
            a8 = fmaf(zv[6], w4b.z, a8);
            a8 = fmaf(zv[7], w4b.w, a8);
        }
        float zqv = (float)tot;
        float da = __fadd_rn(__fsub_rn(zqv, __fmul_rn(2.0f, a8)), wsq[k]);
        unsigned long long key =
            ((unsigned long long)__float_as_uint(da) << 32) | (unsigned int)k;
        atomicMin(&slots[ti], key);
    }
}

// ---------------------------------------------------------------------------
// Final readout (skipped on overflow): out[bt] = winning k from slots.
// ---------------------------------------------------------------------------
__global__ __launch_bounds__(256) void vq_final(const int* __restrict__ gties,
                                                const int* __restrict__ gcnt,
                                                const int* __restrict__ oflow,
                                                const unsigned long long* __restrict__ slots,
                                                int* __restrict__ out) {
    if (*oflow) return;
    const int n = *gcnt;
    for (int j = blockIdx.x * 256 + threadIdx.x; j < n; j += (int)gridDim.x * 256) {
        out[gties[j]] = (int)(slots[j] & 511ULL);
    }
}

// ---------------------------------------------------------------------------
// Full tie fix (R2-validated). Big tier: runs only on overflow (oflow!=0).
// Tier-2: oflow == nullptr -> always runs.
// ---------------------------------------------------------------------------
__global__ __launch_bounds__(256) void vq_fix(const float* __restrict__ Z,
                                              const float* __restrict__ W,
                                              const float* __restrict__ wsq,
                                              const int* __restrict__ gties,
                                              const int* __restrict__ gcnt,
                                              int* __restrict__ out,
                                              const int* __restrict__ oflow) {
    if (oflow != nullptr && *oflow == 0) return;

    __shared__ __align__(16) float Zs[8][256];
    __shared__ double pz[8][32];
    __shared__ float  zsqs[8];
    __shared__ int    bts[8];
    __shared__ float  rv[8][4];
    __shared__ int    ri[8][4];

    const int tid  = threadIdx.x;
    const int lane = tid & 63;
    const int wvx  = tid >> 6;
    const int n    = *gcnt;

    for (int base = blockIdx.x * 8; base < n; base += (int)gridDim.x * 8) {
        const int m = (n - base < 8) ? (n - base) : 8;
        __syncthreads();
        if (tid < 8) bts[tid] = gties[base + ((tid < m) ? tid : 0)];
        __syncthreads();

        #pragma unroll
        for (int i = 0; i < 8; ++i) {
            if (i < m) {
                int tb = bts[i];
                int bb = tb >> 12, t = tb & 4095;
                Zs[i][tid] = Z[(size_t)bb * DD * NT + (size_t)tid * NT + t];
            }
        }
        __syncthreads();

        {
            int i = tid >> 5, seg = tid & 31;
            double s = 0.0;
            #pragma unroll
            for (int j = 0; j < 8; ++j) {
                double zz = (double)Zs[i][seg * 8 + j];
                s = fma(zz, zz, s);
            }
            pz[i][seg] = s;
        }
        __syncthreads();
        if (tid < 8) {
            double s = 0.0;
            #pragma unroll
            for (int j = 0; j < 32; ++j) s += pz[tid][j];
            zsqs[tid] = (float)s;
        }
        __syncthreads();

        float da[2][8];
        #pragma unroll
        for (int rr = 0; rr < 2; ++rr) {
            int k = tid + rr * 256;
            const float4* wr = (const float4*)(W + (size_t)k * DD);
            float a8[8];
            #pragma unroll
            for (int i = 0; i < 8; ++i) a8[i] = 0.f;
            #pragma unroll 2
            for (int q = 0; q < 64; ++q) {
                float4 w4 = wr[q];
                #pragma unroll
                for (int i = 0; i < 8; ++i) {
                    float4 z4 = *(const float4*)&Zs[i][4 * q];   // LDS broadcast
                    a8[i] = fmaf(z4.x, w4.x, a8[i]);
                    a8[i] = fmaf(z4.y, w4.y, a8[i]);
                    a8[i] = fmaf(z4.z, w4.z, a8[i]);
                    a8[i] = fmaf(z4.w, w4.w, a8[i]);
                }
            }
            float wqv = wsq[k];
            #pragma unroll
            for (int i = 0; i < 8; ++i)
                da[rr][i] = __fadd_rn(__fsub_rn(zsqs[i], __fmul_rn(2.0f, a8[i])), wqv);
        }

        #pragma unroll
        for (int i = 0; i < 8; ++i) {
            float v = da[0][i]; int ix = tid;
            if (da[1][i] < v) { v = da[1][i]; ix = tid + 256; }
            #pragma unroll
            for (int mk = 1; mk <= 32; mk <<= 1) {
                float ov = __shfl_xor(v, mk);
                int   oi = __shfl_xor(ix, mk);
                if (ov < v || (ov == v && oi < ix)) { v = ov; ix = oi; }
            }
            if (lane == 0) { rv[i][wvx] = v; ri[i][wvx] = ix; }
        }
        __syncthreads();
        if (tid < 8 && tid < m) {
            float v = INFINITY; int ix = 0x7fffffff;
            #pragma unroll
            for (int w = 0; w < 4; ++w) {
                if (rv[tid][w] < v || (rv[tid][w] == v && ri[tid][w] < ix)) {
                    v = rv[tid][w]; ix = ri[tid][w];
                }
            }
            out[bts[tid]] = ix;
        }
    }
}

// ---------------------------------------------------------------------------
// Phase 1 (tier-2, R2-validated): 4-wave, in-kernel staging.
// ---------------------------------------------------------------------------
__global__ __launch_bounds__(256, 2) void vq_phase1_reg(const float* __restrict__ Z,
                                                        const unsigned short* __restrict__ Wpp,
                                                        const float* __restrict__ wsq,
                                                        int* __restrict__ out,
                                                        int* __restrict__ gties,
                                                        int* __restrict__ gcnt) {
    __shared__ __align__(16) short As[64 * ASTR];
    __shared__ int lcnt, gbase;

    const int tid  = threadIdx.x;
    const int wave = tid >> 6;
    const int lane = tid & 63;
    const int lm   = lane & 15;
    const int lq   = lane >> 4;
    const int nw   = wave;

    const int bx = blockIdx.x;
    const int b  = bx >> 6;
    const int t0 = (bx & 63) * 64;

    const int t_l = tid & 63;
    const int dgs = tid >> 6;

    const float* zcol = Z + (size_t)b * DD * NT + t0 + t_l;

    if (tid == 0) lcnt = 0;

    double zacc = 0.0;
    #pragma unroll
    for (int half = 0; half < 2; ++half) {
        float zv[32];
        #pragma unroll
        for (int j = 0; j < 32; ++j)
            zv[j] = zcol[(size_t)(dgs * 64 + half * 32 + j) * NT];
        #pragma unroll
        for (int j = 0; j < 32; ++j)
            zacc = fma((double)zv[j], (double)zv[j], zacc);
        #pragma unroll
        for (int j0 = 0; j0 < 32; j0 += 4) {
            __align__(16) unsigned int u[4];
            #pragma unroll
            for (int q = 0; q < 4; ++q) {
                float z = zv[j0 + q];
                _Float16 zh = (_Float16)z;
                float rz = z - (float)zh;
                unsigned short hs, ls;
                __builtin_memcpy(&hs, &zh, 2);
                ls = f16bits(rz);
                u[q] = (unsigned int)hs | ((unsigned int)ls << 16);
            }
            *(int4*)&As[t_l * ASTR + (dgs * 64 + half * 32 + j0) * 2] = *(const int4*)u;
        }
    }
    __syncthreads();

    const unsigned short* wb = Wpp + ((size_t)(nw * 128 + lm) * 32) + lq * 8;

    f32x4 acc[4][8];
    #pragma unroll
    for (int mt = 0; mt < 4; ++mt)
        #pragma unroll
        for (int nt = 0; nt < 8; ++nt)
            acc[mt][nt] = (f32x4){0.f, 0.f, 0.f, 0.f};

    int4 bv0[8], bv1[8];
    #pragma unroll
    for (int nt = 0; nt < 8; ++nt)
        bv0[nt] = *(const int4*)(wb + nt * 512);

    #pragma unroll
    for (int c = 0; c < NCH; ++c) {
        int4* cur = (c & 1) ? bv1 : bv0;
        int4* nxt = (c & 1) ? bv0 : bv1;
        if (c < NCH - 1) {
            const unsigned short* wp = wb + (size_t)(c + 1) * 16384;
            #pragma unroll
            for (int nt = 0; nt < 8; ++nt)
                nxt[nt] = *(const int4*)(wp + nt * 512);
        }
        f16x8 a[4];
        #pragma unroll
        for (int mt = 0; mt < 4; ++mt)
            a[mt] = *(const f16x8*)&As[(mt * 16 + lm) * ASTR + c * 32 + lq * 8];
        #pragma unroll
        for (int mt = 0; mt < 4; ++mt)
            #pragma unroll
            for (int nt = 0; nt < 8; ++nt)
                acc[mt][nt] = __builtin_amdgcn_mfma_f32_16x16x32_f16(
                    a[mt], *(const f16x8*)&cur[nt], acc[mt][nt], 0, 0, 0);
    }

    __syncthreads();
    double* zred = (double*)As;
    float*  zf   = (float*)(As + 1024);
    float*  cb1  = (float*)(As + 1536);
    float*  cb2  = (float*)(As + 2048);
    int*    cbi  = (int*)(As + 2560);
    int*    llist = (int*)(As + 3072);

    zred[dgs * 64 + t_l] = zacc;
    __syncthreads();
    if (tid < 64) {
        double s = zred[tid];
        #pragma unroll
        for (int p = 1; p < 4; ++p) s += zred[p * 64 + tid];
        zf[tid] = (float)s;
    }
    __syncthreads();

    float wq[8];
    #pragma unroll
    for (int nt = 0; nt < 8; ++nt)
        wq[nt] = wsq[nw * 128 + nt * 16 + lm];
    const int kbase = nw * 128 + lm;

    #pragma unroll
    for (int mt = 0; mt < 4; ++mt) {
        #pragma unroll
        for (int r = 0; r < 4; ++r) {
            float zz = zf[mt * 16 + lq * 4 + r];
            float q1 = INFINITY, q2 = INFINITY;
            int i1 = 0x7fffffff;
            #pragma unroll
            for (int nt = 0; nt < 8; ++nt) {
                float c2   = __fmul_rn(acc[mt][nt][r], 4.8828125e-4f);
                float dist = __fadd_rn(__fsub_rn(zz, c2), wq[nt]);
                int kk = kbase + nt * 16;
                if (dist < q1 || (dist == q1 && kk < i1)) { q2 = q1; q1 = dist; i1 = kk; }
                else if (dist < q2) q2 = dist;
            }
            #pragma unroll
            for (int mk = 1; mk <= 8; mk <<= 1) {
                float o1 = __shfl_xor(q1, mk);
                float o2 = __shfl_xor(q2, mk);
                int   oi = __shfl_xor(i1, mk);
                if (o1 < q1 || (o1 == q1 && oi < i1)) { q2 = fminf(q1, o2); q1 = o1; i1 = oi; }
                else { q2 = fminf(o1, q2); }
            }
            if (lm == 0) {
                int m = mt * 16 + lq * 4 + r;
                cb1[m * 4 + nw] = q1;
                cb2[m * 4 + nw] = q2;
                cbi[m * 4 + nw] = i1;
            }
        }
    }
    __syncthreads();
    if (tid < 64) {
        float q1 = cb1[tid * 4], q2 = cb2[tid * 4];
        int   i1 = cbi[tid * 4];
        #pragma unroll
        for (int p = 1; p < 4; ++p) {
            float c1 = cb1[tid * 4 + p], c2v = cb2[tid * 4 + p];
            int   ci = cbi[tid * 4 + p];
            if (c1 < q1 || (c1 == q1 && ci < i1)) { q2 = fminf(q1, c2v); q1 = c1; i1 = ci; }
            else { q2 = fminf(q2, c1); }
        }
        out[(size_t)b * NT + t0 + tid] = i1;
        if (q2 - q1 <= MARGIN) {
            int p = atomicAdd(&lcnt, 1);
            llist[p] = b * NT + t0 + tid;
        }
    }
    __syncthreads();
    if (tid == 0) gbase = (lcnt > 0) ? atomicAdd(gcnt, lcnt) : 0;
    __syncthreads();
    if (tid < lcnt) gties[gbase + tid] = llist[tid];
}

// ---------------------------------------------------------------------------
// Fallback (R1 kernel) if ws is too small.
// ---------------------------------------------------------------------------
#define BT 128
#define BK 128
#define DCHUNK 32
#define NKC (NK / BK)
#define NDC (DD / DCHUNK)
#define WSTR (BK + 4)

__global__ __launch_bounds__(256) void vq_fallback(const float* __restrict__ Z,
                                                   const float* __restrict__ W,
                                                   int* __restrict__ out) {
    __shared__ __align__(16) float Zs[DCHUNK * BT];
    __shared__ __align__(16) float Ws[DCHUNK * WSTR];
    __shared__ float wsqs[NK];

    const int tid = threadIdx.x;
    const int tx  = tid & 15;
    const int ty  = tid >> 4;
    const int b   = blockIdx.y;
    const int t0  = blockIdx.x * BT;

    for (int k = tid; k < NK; k += 256) {
        const float4* row = (const float4*)(W + (size_t)k * DD);
        double s = 0.0;
        for (int i = 0; i < DD / 4; ++i) {
            float4 v = row[i];
            s += (double)v.x * v.x + (double)v.y * v.y + (double)v.z * v.z + (double)v.w * v.w;
        }
        wsqs[k] = (float)s;
    }

    const float* Zb = Z + (size_t)b * DD * NT + t0;

    float best[8]; int bidx[8];
    #pragma unroll
    for (int a = 0; a < 8; ++a) { best[a] = INFINITY; bidx[a] = 0x7fffffff; }
    double zsqd[8];
    #pragma unroll
    for (int a = 0; a < 8; ++a) zsqd[a] = 0.0;
    float zsqf[8];

    for (int kc = 0; kc < NKC; ++kc) {
        float acc[8][8];
        #pragma unroll
        for (int a = 0; a < 8; ++a)
            #pragma unroll
            for (int c = 0; c < 8; ++c) acc[a][c] = 0.f;

        for (int dc = 0; dc < NDC; ++dc) {
            const int d0 = dc * DCHUNK;
            __syncthreads();
            #pragma unroll
            for (int i = 0; i < 4; ++i) {
                int f  = tid + i * 256;
                int r  = f >> 5;
                int c4 = f & 31;
                float4 v = *(const float4*)(Zb + (size_t)(d0 + r) * NT + c4 * 4);
                *(float4*)(&Zs[r * BT + c4 * 4]) = v;
            }
            #pragma unroll
            for (int i = 0; i < 4; ++i) {
                int u  = tid + i * 256;
                int k  = u >> 3;
                int rg = u & 7;
                float4 v = *(const float4*)(W + (size_t)(kc * BK + k) * DD + d0 + rg * 4);
                Ws[(rg * 4 + 0) * WSTR + k] = v.x;
                Ws[(rg * 4 + 1) * WSTR + k] = v.y;
                Ws[(rg * 4 + 2) * WSTR + k] = v.z;
                Ws[(rg * 4 + 3) * WSTR + k] = v.w;
            }
            __syncthreads();
            #pragma unroll 4
            for (int d = 0; d < DCHUNK; ++d) {
                float4 z0 = *(const float4*)(&Zs[d * BT + ty * 8]);
                float4 z1 = *(const float4*)(&Zs[d * BT + ty * 8 + 4]);
                float4 w0 = *(const float4*)(&Ws[d * WSTR + tx * 8]);
                float4 w1 = *(const float4*)(&Ws[d * WSTR + tx * 8 + 4]);
                float za[8] = {z0.x, z0.y, z0.z, z0.w, z1.x, z1.y, z1.z, z1.w};
                float wa[8] = {w0.x, w0.y, w0.z, w0.w, w1.x, w1.y, w1.z, w1.w};
                if (kc == 0) {
                    #pragma unroll
                    for (int a = 0; a < 8; ++a)
                        zsqd[a] = fma((double)za[a], (double)za[a], zsqd[a]);
                }
                #pragma unroll
                for (int a = 0; a < 8; ++a)
                    #pragma unroll
                    for (int c = 0; c < 8; ++c)
                        acc[a][c] = fmaf(za[a], wa[c], acc[a][c]);
            }
        }
        if (kc == 0) {
            #pragma unroll
            for (int a = 0; a < 8; ++a) zsqf[a] = (float)zsqd[a];
        }
        #pragma unroll
        for (int c = 0; c < 8; ++c) {
            int   kg = kc * BK + tx * 8 + c;
            float wqv = wsqs[kg];
            #pragma unroll
            for (int a = 0; a < 8; ++a) {
                float c2   = __fmul_rn(2.0f, acc[a][c]);
                float s    = __fsub_rn(zsqf[a], c2);
                float dist = __fadd_rn(s, wqv);
                if (dist < best[a] || (dist == best[a] && kg < bidx[a])) {
                    best[a] = dist; bidx[a] = kg;
                }
            }
        }
    }
    __syncthreads();
    float* redv = Zs;
    int*   redi = (int*)Ws;
    #pragma unroll
    for (int a = 0; a < 8; ++a) {
        int tl2 = ty * 8 + a;
        redv[tl2 * 16 + tx] = best[a];
        redi[tl2 * 16 + tx] = bidx[a];
    }
    __syncthreads();
    if (tid < BT) {
        float bv = INFINITY; int bi = 0x7fffffff;
        #pragma unroll
        for (int j = 0; j < 16; ++j) {
            float v = redv[tid * 16 + j];
            int   i = redi[tid * 16 + j];
            if (v < bv || (v == bv && i < bi)) { bv = v; bi = i; }
        }
        out[(size_t)b * NT + t0 + tid] = bi;
    }
}

extern "C" void kernel_launch(void* const* d_in, const int* in_sizes, int n_in,
                              void* d_out, int out_size, void* d_ws, size_t ws_size,
                              hipStream_t stream) {
    const float* Z = (const float*)d_in[0];   // [B, D, T]
    const float* W = (const float*)d_in[1];   // [K, D]
    int* out = (int*)d_out;                   // [B, T]

    // ---- tier-big layout (~5.8 MB)
    const size_t OFF_WSQ  = 0;                         // 512 f32
    const size_t OFF_CNT  = 2048;                      // gcnt
    const size_t OFF_PCNT = 2052;                      // pcnt
    const size_t OFF_OFL  = 2056;                      // oflow
    const size_t OFF_WPP  = 4096;                      // 512 KB
    const size_t OFF_TIE  = OFF_WPP + 524288;          // 131072 ints (512 KB)
    const size_t OFF_SLOT = OFF_TIE + 524288;          // 131072 u64 (1 MB)
    const size_t OFF_PAIR = OFF_SLOT + 1048576;        // PCAP ints (2 MB)
    const size_t NEED_BIG = OFF_PAIR + (size_t)PCAP * 4;

    // ---- tier-2 layout (R2 path)
    const size_t T2_WSQ = 0;
    const size_t T2_CNT = 2048;
    const size_t T2_WPP = 4096;
    const size_t T2_TIE = T2_WPP + 524288;
    const size_t NEED_T2 = T2_TIE + 524288;

    if (ws_size >= NEED_BIG) {
        float* wsq  = (float*)((char*)d_ws + OFF_WSQ);
        int*   gcnt = (int*)((char*)d_ws + OFF_CNT);
        int*   pcnt = (int*)((char*)d_ws + OFF_PCNT);
        int*   ofl  = (int*)((char*)d_ws + OFF_OFL);
        unsigned short* wpp = (unsigned short*)((char*)d_ws + OFF_WPP);
        int*   gties = (int*)((char*)d_ws + OFF_TIE);
        unsigned long long* slots = (unsigned long long*)((char*)d_ws + OFF_SLOT);
        int*   gpairs = (int*)((char*)d_ws + OFF_PAIR);

        prep_kernel<<<dim3(NCH + 1), dim3(512), 0, stream>>>(W, wpp, wsq, gcnt, pcnt, ofl);
        vq_phase1<<<dim3(2048), dim3(256), 0, stream>>>(Z, wpp, wsq, out, gties, gcnt,
                                                        slots, gpairs, pcnt, ofl);
        vq_fix_pairs<<<dim3(256), dim3(256), 0, stream>>>(Z, W, wsq, gties, gpairs, pcnt, slots);
        vq_fix<<<dim3(256), dim3(256), 0, stream>>>(Z, W, wsq, gties, gcnt, out, ofl);
        vq_final<<<dim3(256), dim3(256), 0, stream>>>(gties, gcnt, ofl, slots, out);
    } else if (ws_size >= NEED_T2) {
        float* wsq  = (float*)((char*)d_ws + T2_WSQ);
        int*   gcnt = (int*)((char*)d_ws + T2_CNT);
        unsigned short* wpp = (unsigned short*)((char*)d_ws + T2_WPP);
        int*   gties = (int*)((char*)d_ws + T2_TIE);

        prep_kernel<<<dim3(NCH + 1), dim3(512), 0, stream>>>(W, wpp, wsq, gcnt, gcnt, gcnt);
        vq_phase1_reg<<<dim3(2048), dim3(256), 0, stream>>>(Z, wpp, wsq, out, gties, gcnt);
        vq_fix<<<dim3(256), dim3(256), 0, stream>>>(Z, W, wsq, gties, gcnt, out, nullptr);
    } else {
        vq_fallback<<<dim3(NT / BT, NB), dim3(256), 0, stream>>>(Z, W, out);
    }
}

// Round 9
// 358.884 us; speedup vs baseline: 1.0954x; 1.0026x over previous
//
#include <hip/hip_runtime.h>
#include <math.h>

#define NK 512
#define DD 256
#define NB 32
#define NT 4096

typedef __attribute__((ext_vector_type(8))) _Float16 f16x8;
typedef __attribute__((ext_vector_type(4))) float f32x4;

#define MARGIN 1.5e-4f
#define DCH 16      // d per chunk
#define NCH 16      // chunks (DD/DCH)
#define ASTR 536    // LDS row stride in shorts (1072 B: 268 dw, 268%32=12 -> 2-way max)
#define PCAP   524288      // global pair capacity
#define PBCAP  2048        // per-block pair list capacity (LDS overlay)
#define ZCROWS 65536       // Zc capacity (tokens); overflow -> guarded full fix
#define ZCMAX  48          // per-block colbuf capacity (ties per 64-token block)

__device__ __forceinline__ unsigned short f16bits(float x) {
    _Float16 h = (_Float16)x;           // v_cvt_f16_f32, RNE
    unsigned short s;
    __builtin_memcpy(&s, &h, 2);
    return s;
}

// ---------------------------------------------------------------------------
// Prep W: blocks 0..15 build Wpp (f16 w*4096, duplicated per-d slot pair);
// block 16 computes wsq (fp64 -> fp32 once) and zeroes counters.
// ---------------------------------------------------------------------------
__global__ __launch_bounds__(512) void prep_kernel(const float* __restrict__ W,
                                                   unsigned short* __restrict__ Wpp,
                                                   float* __restrict__ wsq,
                                                   int* __restrict__ gcnt,
                                                   int* __restrict__ pcnt,
                                                   int* __restrict__ oflow) {
    const int bx = blockIdx.x;
    const int k  = threadIdx.x;   // 0..511
    if (bx < NCH) {
        const int d0 = bx * DCH;
        float w[16];
        const float4* src4 = (const float4*)(W + (size_t)k * DD + d0);
        #pragma unroll
        for (int q = 0; q < 4; ++q) {
            float4 v = src4[q];
            w[4 * q + 0] = v.x; w[4 * q + 1] = v.y; w[4 * q + 2] = v.z; w[4 * q + 3] = v.w;
        }
        __align__(16) unsigned int dw[16];
        #pragma unroll
        for (int j = 0; j < 16; ++j) {
            unsigned short s = f16bits(w[j] * 4096.0f);  // exact pow2 scale, then RNE
            dw[j] = (unsigned int)s | ((unsigned int)s << 16);  // (wh, wh) slot pair
        }
        unsigned short* dst = Wpp + ((size_t)bx * 512 + k) * 32;
        #pragma unroll
        for (int j = 0; j < 4; ++j) ((int4*)dst)[j] = ((const int4*)dw)[j];
    } else {
        const float4* row = (const float4*)(W + (size_t)k * DD);
        double s = 0.0;
        #pragma unroll 8
        for (int i = 0; i < DD / 4; ++i) {
            float4 v = row[i];
            s += (double)v.x * v.x + (double)v.y * v.y + (double)v.z * v.z + (double)v.w * v.w;
        }
        wsq[k] = (float)s;
        if (k == 0) *gcnt = 0;
        if (k == 1) *pcnt = 0;
        if (k == 2) *oflow = 0;
    }
}

// ---------------------------------------------------------------------------
// Phase 1 (big tier) = the R2/R8-measured-best K-loop (block = 64 t x 512
// codes, 256 thr / 4 waves, acc[4][8], barrier-free, B depth-1 named dbuf
// from L2). Epilogue: light tie emit + PARALLEL gated Zc gather:
//   - d-major reads (tie lanes hit one 256B window per d -> <=4 lines)
//     into +1-padded LDS colbuf (bank-conflict-free),
//   - coalesced 1KB row writes to Zc,
//   - thread-per-token exact fp64 zq (validated seg-ordered chain).
// All approx-path numerics bit-identical to the validated kernel.
// ---------------------------------------------------------------------------
__global__ __launch_bounds__(256, 2) void vq_phase1(const float* __restrict__ Z,
                                                    const unsigned short* __restrict__ Wpp,
                                                    const float* __restrict__ wsq,
                                                    int* __restrict__ out,
                                                    int* __restrict__ gties,
                                                    int* __restrict__ gcnt,
                                                    float* __restrict__ Zc,
                                                    float* __restrict__ zq,
                                                    unsigned long long* __restrict__ slots,
                                                    int* __restrict__ gpairs,
                                                    int* __restrict__ pcnt,
                                                    int* __restrict__ oflow) {
    __shared__ __align__(16) short As[64 * ASTR];   // 68,608 B
    __shared__ int lcnt, gbase, pcl, pbase_sh;

    const int tid  = threadIdx.x;
    const int wave = tid >> 6;
    const int lane = tid & 63;
    const int lm   = lane & 15;
    const int lq   = lane >> 4;
    const int nw   = wave;        // k quarter (128 codes)

    const int bx = blockIdx.x;
    const int b  = bx >> 6;
    const int t0 = (bx & 63) * 64;

    const int t_l = tid & 63;
    const int dgs = tid >> 6;     // 0..3, 64 d each

    const float* zcol = Z + (size_t)b * DD * NT + t0 + t_l;

    if (tid == 0) { lcnt = 0; pcl = 0; }

    // ---- staging: exact validated per-thread chain (64 loads, fp64, split)
    double zacc = 0.0;
    #pragma unroll
    for (int half = 0; half < 2; ++half) {
        float zv[32];
        #pragma unroll
        for (int j = 0; j < 32; ++j)
            zv[j] = zcol[(size_t)(dgs * 64 + half * 32 + j) * NT];
        #pragma unroll
        for (int j = 0; j < 32; ++j)
            zacc = fma((double)zv[j], (double)zv[j], zacc);
        #pragma unroll
        for (int j0 = 0; j0 < 32; j0 += 4) {
            __align__(16) unsigned int u[4];
            #pragma unroll
            for (int q = 0; q < 4; ++q) {
                float z = zv[j0 + q];
                _Float16 zh = (_Float16)z;
                float rz = z - (float)zh;     // exact (Sterbenz)
                unsigned short hs, ls;
                __builtin_memcpy(&hs, &zh, 2);
                ls = f16bits(rz);
                u[q] = (unsigned int)hs | ((unsigned int)ls << 16);  // (zh, zl)
            }
            *(int4*)&As[t_l * ASTR + (dgs * 64 + half * 32 + j0) * 2] = *(const int4*)u;
        }
    }
    __syncthreads();   // staging visible; the ONLY pre-epilogue barrier

    const unsigned short* wb = Wpp + ((size_t)(nw * 128 + lm) * 32) + lq * 8;

    f32x4 acc[4][8];
    #pragma unroll
    for (int mt = 0; mt < 4; ++mt)
        #pragma unroll
        for (int nt = 0; nt < 8; ++nt)
            acc[mt][nt] = (f32x4){0.f, 0.f, 0.f, 0.f};

    int4 bv0[8], bv1[8];
    #pragma unroll
    for (int nt = 0; nt < 8; ++nt)
        bv0[nt] = *(const int4*)(wb + nt * 512);

    #pragma unroll
    for (int c = 0; c < NCH; ++c) {
        int4* cur = (c & 1) ? bv1 : bv0;
        int4* nxt = (c & 1) ? bv0 : bv1;
        if (c < NCH - 1) {
            const unsigned short* wp = wb + (size_t)(c + 1) * 16384;
            #pragma unroll
            for (int nt = 0; nt < 8; ++nt)
                nxt[nt] = *(const int4*)(wp + nt * 512);
        }
        f16x8 a[4];
        #pragma unroll
        for (int mt = 0; mt < 4; ++mt)
            a[mt] = *(const f16x8*)&As[(mt * 16 + lm) * ASTR + c * 32 + lq * 8];
        #pragma unroll
        for (int mt = 0; mt < 4; ++mt)
            #pragma unroll
            for (int nt = 0; nt < 8; ++nt)
                acc[mt][nt] = __builtin_amdgcn_mfma_f32_16x16x32_f16(
                    a[mt], *(const f16x8*)&cur[nt], acc[mt][nt], 0, 0, 0);
    }

    // ---- epilogue. LDS overlay (As free after K-loop).
    __syncthreads();
    char* base = (char*)As;
    double* zred  = (double*)base;              // [4][64]  2048 B
    float*  zf    = (float*)(base + 2048);      // 64
    float*  qf    = (float*)(base + 2304);      // 64
    int*    tia   = (int*)(base + 2560);        // 64
    int*    ltok  = (int*)(base + 2816);        // 64
    float*  cb1   = (float*)(base + 3072);      // [64][4]
    float*  cb2   = (float*)(base + 4096);
    int*    cbi   = (int*)(base + 5120);
    int*    plist = (int*)(base + 6144);        // PBCAP ints (8 KB) -> ends 14336
    float*  colbuf = (float*)(base + 14336);    // [ZCMAX][257] = 49,344 B -> 63,680

    zred[dgs * 64 + t_l] = zacc;
    __syncthreads();
    if (tid < 64) {
        double s = zred[tid];
        #pragma unroll
        for (int p = 1; p < 4; ++p) s += zred[p * 64 + tid];
        zf[tid] = (float)s;
    }
    __syncthreads();

    float wq[8];
    #pragma unroll
    for (int nt = 0; nt < 8; ++nt)
        wq[nt] = wsq[nw * 128 + nt * 16 + lm];
    const int kbase = nw * 128 + lm;

    #pragma unroll
    for (int mt = 0; mt < 4; ++mt) {
        #pragma unroll
        for (int r = 0; r < 4; ++r) {
            float zz = zf[mt * 16 + lq * 4 + r];
            float q1 = INFINITY, q2 = INFINITY;
            int i1 = 0x7fffffff;
            #pragma unroll
            for (int nt = 0; nt < 8; ++nt) {
                // acc holds cross*2^12; fl(2*cross) = acc * 2^-11 (exact pow2)
                float c2   = __fmul_rn(acc[mt][nt][r], 4.8828125e-4f);
                float dist = __fadd_rn(__fsub_rn(zz, c2), wq[nt]);
                int kk = kbase + nt * 16;
                if (dist < q1 || (dist == q1 && kk < i1)) { q2 = q1; q1 = dist; i1 = kk; }
                else if (dist < q2) q2 = dist;
            }
            #pragma unroll
            for (int mk = 1; mk <= 8; mk <<= 1) {
                float o1 = __shfl_xor(q1, mk);
                float o2 = __shfl_xor(q2, mk);
                int   oi = __shfl_xor(i1, mk);
                if (o1 < q1 || (o1 == q1 && oi < i1)) { q2 = fminf(q1, o2); q1 = o1; i1 = oi; }
                else { q2 = fminf(o1, q2); }
            }
            if (lm == 0) {
                int m = mt * 16 + lq * 4 + r;
                cb1[m * 4 + nw] = q1;
                cb2[m * 4 + nw] = q2;
                cbi[m * 4 + nw] = i1;
            }
        }
    }
    __syncthreads();
    if (tid < 64) {
        float q1 = cb1[tid * 4], q2 = cb2[tid * 4];
        int   i1 = cbi[tid * 4];
        #pragma unroll
        for (int p = 1; p < 4; ++p) {
            float c1 = cb1[tid * 4 + p], c2v = cb2[tid * 4 + p];
            int   ci = cbi[tid * 4 + p];
            if (c1 < q1 || (c1 == q1 && ci < i1)) { q2 = fminf(q1, c2v); q1 = c1; i1 = ci; }
            else { q2 = fminf(q2, c1); }
        }
        out[(size_t)b * NT + t0 + tid] = i1;
        qf[tid] = q1;
        int ta = -1;
        if (q2 - q1 <= MARGIN) {
            ta = atomicAdd(&lcnt, 1);
            ltok[ta] = tid;
        }
        tia[tid] = ta;
    }
    __syncthreads();           // merge done; lcnt/qf/tia final
    const int nloc = lcnt;
    if (nloc == 0) return;

    if (tid == 0) gbase = atomicAdd(gcnt, nloc);
    __syncthreads();

    // gties always written (full-fix backstop needs them)
    if (tid < nloc) gties[gbase + tid] = b * NT + t0 + ltok[tid];

    const bool okzc = (gbase + nloc <= ZCROWS) && (nloc <= ZCMAX);
    if (!okzc) {
        if (tid == 0) *oflow = 1;
        return;                 // full-fix backstop resolves these ties
    }
    if (tid < nloc) slots[gbase + tid] = 0xFFFFFFFFFFFFFFFFULL;

    // ---- single-pass candidate emit: dists are live in registers
    #pragma unroll
    for (int mt = 0; mt < 4; ++mt) {
        #pragma unroll
        for (int r = 0; r < 4; ++r) {
            const int tok = mt * 16 + lq * 4 + r;
            const int ta  = tia[tok];
            if (ta < 0) continue;
            const int ti  = gbase + ta;
            const float thr = qf[tok] + MARGIN;
            const float zz  = zf[tok];
            #pragma unroll
            for (int nt = 0; nt < 8; ++nt) {
                float c2   = __fmul_rn(acc[mt][nt][r], 4.8828125e-4f);
                float dist = __fadd_rn(__fsub_rn(zz, c2), wq[nt]);
                if (dist <= thr) {
                    int p = atomicAdd(&pcl, 1);
                    if (p < PBCAP) plist[p] = (ti << 9) | (kbase + nt * 16);
                }
            }
        }
    }
    __syncthreads();
    if (tid == 0) {
        int take = pcl;
        int bs = atomicAdd(pcnt, take);
        pbase_sh = bs;
        if (take > PBCAP || bs + take > PCAP) *oflow = 1;
    }
    __syncthreads();
    {
        int take = pcl; if (take > PBCAP) take = PBCAP;
        for (int j = tid; j < take; j += 256) {
            int gp = pbase_sh + j;
            if (gp < PCAP) gpairs[gp] = plist[j];
        }
    }

    // ---- parallel tie gather: d-major (tie lanes hit one 256B window per d)
    {
        const int i  = tid & 63;
        const int dw = tid >> 6;          // 0..3
        for (int du = 0; du < 64; ++du) {
            const int d = du * 4 + dw;
            if (i < nloc)
                colbuf[i * 257 + d] =
                    Z[(size_t)b * DD * NT + (size_t)d * NT + (t0 + ltok[i])];
        }
    }
    __syncthreads();
    // coalesced Zc row writes (256 lanes per 1KB row)
    for (int i = 0; i < nloc; ++i)
        Zc[(size_t)(gbase + i) * 256 + tid] = colbuf[i * 257 + tid];
    // exact zq, thread-per-token (validated seg-ordered fp64 chain)
    if (tid < nloc) {
        const float* cp = colbuf + tid * 257;
        double tot = 0.0;
        for (int seg = 0; seg < 32; ++seg) {
            double s = 0.0;
            #pragma unroll
            for (int jj = 0; jj < 8; ++jj) {
                double zz = (double)cp[seg * 8 + jj];
                s = fma(zz, zz, s);
            }
            tot += s;
        }
        zq[gbase + tid] = (float)tot;
    }
}

// ---------------------------------------------------------------------------
// Pair fix (R4-validated): one thread per (tie-token, candidate-code) pair;
// exact fp32 fmaf chain over the COMPACT coalesced Zc row + precomputed zq.
// Winner per token via 64-bit atomicMin on (dist_bits<<32 | k) — dist > 0 so
// bit order = value order; ties pick smaller k (the validated comparator).
// ---------------------------------------------------------------------------
__global__ __launch_bounds__(256) void vq_fix_pairs(const float* __restrict__ W,
                                                    const float* __restrict__ wsq,
                                                    const float* __restrict__ Zc,
                                                    const float* __restrict__ zq,
                                                    const int* __restrict__ gpairs,
                                                    const int* __restrict__ pcnt,
                                                    unsigned long long* __restrict__ slots) {
    int np = *pcnt;
    if (np > PCAP) np = PCAP;
    for (int j = blockIdx.x * 256 + threadIdx.x; j < np; j += (int)gridDim.x * 256) {
        const int p  = gpairs[j];
        const int ti = p >> 9;
        const int k  = p & 511;
        if (ti >= ZCROWS) continue;
        const float4* zr = (const float4*)(Zc + (size_t)ti * 256);
        const float4* wr = (const float4*)(W + (size_t)k * DD);
        float a8 = 0.f;
        #pragma unroll 4
        for (int q = 0; q < 64; ++q) {
            float4 w4 = wr[q];
            float4 z4 = zr[q];
            a8 = fmaf(z4.x, w4.x, a8);
            a8 = fmaf(z4.y, w4.y, a8);
            a8 = fmaf(z4.z, w4.z, a8);
            a8 = fmaf(z4.w, w4.w, a8);
        }
        float da = __fadd_rn(__fsub_rn(zq[ti], __fmul_rn(2.0f, a8)), wsq[k]);
        unsigned long long key =
            ((unsigned long long)__float_as_uint(da) << 32) | (unsigned int)k;
        atomicMin(&slots[ti], key);
    }
}

// ---------------------------------------------------------------------------
// Final readout (skipped on overflow): out[bt] = winning k from slots.
// ---------------------------------------------------------------------------
__global__ __launch_bounds__(256) void vq_final(const int* __restrict__ gties,
                                                const int* __restrict__ gcnt,
                                                const int* __restrict__ oflow,
                                                const unsigned long long* __restrict__ slots,
                                                int* __restrict__ out) {
    if (*oflow) return;
    const int n = *gcnt;
    for (int j = blockIdx.x * 256 + threadIdx.x; j < n; j += (int)gridDim.x * 256) {
        out[gties[j]] = (int)(slots[j] & 511ULL);
    }
}

// ---------------------------------------------------------------------------
// Full tie fix (R2-validated). Big tier: runs only on overflow (oflow!=0).
// Tier-2: oflow == nullptr -> always runs.
// ---------------------------------------------------------------------------
__global__ __launch_bounds__(256) void vq_fix(const float* __restrict__ Z,
                                              const float* __restrict__ W,
                                              const float* __restrict__ wsq,
                                              const int* __restrict__ gties,
                                              const int* __restrict__ gcnt,
                                              int* __restrict__ out,
                                              const int* __restrict__ oflow) {
    if (oflow != nullptr && *oflow == 0) return;

    __shared__ __align__(16) float Zs[8][256];
    __shared__ double pz[8][32];
    __shared__ float  zsqs[8];
    __shared__ int    bts[8];
    __shared__ float  rv[8][4];
    __shared__ int    ri[8][4];

    const int tid  = threadIdx.x;
    const int lane = tid & 63;
    const int wvx  = tid >> 6;
    const int n    = *gcnt;

    for (int base = blockIdx.x * 8; base < n; base += (int)gridDim.x * 8) {
        const int m = (n - base < 8) ? (n - base) : 8;
        __syncthreads();
        if (tid < 8) bts[tid] = gties[base + ((tid < m) ? tid : 0)];
        __syncthreads();

        #pragma unroll
        for (int i = 0; i < 8; ++i) {
            if (i < m) {
                int tb = bts[i];
                int bb = tb >> 12, t = tb & 4095;
                Zs[i][tid] = Z[(size_t)bb * DD * NT + (size_t)tid * NT + t];
            }
        }
        __syncthreads();

        {
            int i = tid >> 5, seg = tid & 31;
            double s = 0.0;
            #pragma unroll
            for (int j = 0; j < 8; ++j) {
                double zz = (double)Zs[i][seg * 8 + j];
                s = fma(zz, zz, s);
            }
            pz[i][seg] = s;
        }
        __syncthreads();
        if (tid < 8) {
            double s = 0.0;
            #pragma unroll
            for (int j = 0; j < 32; ++j) s += pz[tid][j];
            zsqs[tid] = (float)s;
        }
        __syncthreads();

        float da[2][8];
        #pragma unroll
        for (int rr = 0; rr < 2; ++rr) {
            int k = tid + rr * 256;
            const float4* wr = (const float4*)(W + (size_t)k * DD);
            float a8[8];
            #pragma unroll
            for (int i = 0; i < 8; ++i) a8[i] = 0.f;
            #pragma unroll 2
            for (int q = 0; q < 64; ++q) {
                float4 w4 = wr[q];
                #pragma unroll
                for (int i = 0; i < 8; ++i) {
                    float4 z4 = *(const float4*)&Zs[i][4 * q];   // LDS broadcast
                    a8[i] = fmaf(z4.x, w4.x, a8[i]);
                    a8[i] = fmaf(z4.y, w4.y, a8[i]);
                    a8[i] = fmaf(z4.z, w4.z, a8[i]);
                    a8[i] = fmaf(z4.w, w4.w, a8[i]);
                }
            }
            float wqv = wsq[k];
            #pragma unroll
            for (int i = 0; i < 8; ++i)
                da[rr][i] = __fadd_rn(__fsub_rn(zsqs[i], __fmul_rn(2.0f, a8[i])), wqv);
        }

        #pragma unroll
        for (int i = 0; i < 8; ++i) {
            float v = da[0][i]; int ix = tid;
            if (da[1][i] < v) { v = da[1][i]; ix = tid + 256; }
            #pragma unroll
            for (int mk = 1; mk <= 32; mk <<= 1) {
                float ov = __shfl_xor(v, mk);
                int   oi = __shfl_xor(ix, mk);
                if (ov < v || (ov == v && oi < ix)) { v = ov; ix = oi; }
            }
            if (lane == 0) { rv[i][wvx] = v; ri[i][wvx] = ix; }
        }
        __syncthreads();
        if (tid < 8 && tid < m) {
            float v = INFINITY; int ix = 0x7fffffff;
            #pragma unroll
            for (int w = 0; w < 4; ++w) {
                if (rv[tid][w] < v || (rv[tid][w] == v && ri[tid][w] < ix)) {
                    v = rv[tid][w]; ix = ri[tid][w];
                }
            }
            out[bts[tid]] = ix;
        }
    }
}

// ---------------------------------------------------------------------------
// Phase 1 (tier-2, R2-validated): 4-wave, in-kernel staging.
// ---------------------------------------------------------------------------
__global__ __launch_bounds__(256, 2) void vq_phase1_reg(const float* __restrict__ Z,
                                                        const unsigned short* __restrict__ Wpp,
                                                        const float* __restrict__ wsq,
                                                        int* __restrict__ out,
                                                        int* __restrict__ gties,
                                                        int* __restrict__ gcnt) {
    __shared__ __align__(16) short As[64 * ASTR];
    __shared__ int lcnt, gbase;

    const int tid  = threadIdx.x;
    const int wave = tid >> 6;
    const int lane = tid & 63;
    const int lm   = lane & 15;
    const int lq   = lane >> 4;
    const int nw   = wave;

    const int bx = blockIdx.x;
    const int b  = bx >> 6;
    const int t0 = (bx & 63) * 64;

    const int t_l = tid & 63;
    const int dgs = tid >> 6;

    const float* zcol = Z + (size_t)b * DD * NT + t0 + t_l;

    if (tid == 0) lcnt = 0;

    double zacc = 0.0;
    #pragma unroll
    for (int half = 0; half < 2; ++half) {
        float zv[32];
        #pragma unroll
        for (int j = 0; j < 32; ++j)
            zv[j] = zcol[(size_t)(dgs * 64 + half * 32 + j) * NT];
        #pragma unroll
        for (int j = 0; j < 32; ++j)
            zacc = fma((double)zv[j], (double)zv[j], zacc);
        #pragma unroll
        for (int j0 = 0; j0 < 32; j0 += 4) {
            __align__(16) unsigned int u[4];
            #pragma unroll
            for (int q = 0; q < 4; ++q) {
                float z = zv[j0 + q];
                _Float16 zh = (_Float16)z;
                float rz = z - (float)zh;
                unsigned short hs, ls;
                __builtin_memcpy(&hs, &zh, 2);
                ls = f16bits(rz);
                u[q] = (unsigned int)hs | ((unsigned int)ls << 16);
            }
            *(int4*)&As[t_l * ASTR + (dgs * 64 + half * 32 + j0) * 2] = *(const int4*)u;
        }
    }
    __syncthreads();

    const unsigned short* wb = Wpp + ((size_t)(nw * 128 + lm) * 32) + lq * 8;

    f32x4 acc[4][8];
    #pragma unroll
    for (int mt = 0; mt < 4; ++mt)
        #pragma unroll
        for (int nt = 0; nt < 8; ++nt)
            acc[mt][nt] = (f32x4){0.f, 0.f, 0.f, 0.f};

    int4 bv0[8], bv1[8];
    #pragma unroll
    for (int nt = 0; nt < 8; ++nt)
        bv0[nt] = *(const int4*)(wb + nt * 512);

    #pragma unroll
    for (int c = 0; c < NCH; ++c) {
        int4* cur = (c & 1) ? bv1 : bv0;
        int4* nxt = (c & 1) ? bv0 : bv1;
        if (c < NCH - 1) {
            const unsigned short* wp = wb + (size_t)(c + 1) * 16384;
            #pragma unroll
            for (int nt = 0; nt < 8; ++nt)
                nxt[nt] = *(const int4*)(wp + nt * 512);
        }
        f16x8 a[4];
        #pragma unroll
        for (int mt = 0; mt < 4; ++mt)
            a[mt] = *(const f16x8*)&As[(mt * 16 + lm) * ASTR + c * 32 + lq * 8];
        #pragma unroll
        for (int mt = 0; mt < 4; ++mt)
            #pragma unroll
            for (int nt = 0; nt < 8; ++nt)
                acc[mt][nt] = __builtin_amdgcn_mfma_f32_16x16x32_f16(
                    a[mt], *(const f16x8*)&cur[nt], acc[mt][nt], 0, 0, 0);
    }

    __syncthreads();
    double* zred = (double*)As;
    float*  zf   = (float*)(As + 1024);
    float*  cb1  = (float*)(As + 1536);
    float*  cb2  = (float*)(As + 2048);
    int*    cbi  = (int*)(As + 2560);
    int*    llist = (int*)(As + 3072);

    zred[dgs * 64 + t_l] = zacc;
    __syncthreads();
    if (tid < 64) {
        double s = zred[tid];
        #pragma unroll
        for (int p = 1; p < 4; ++p) s += zred[p * 64 + tid];
        zf[tid] = (float)s;
    }
    __syncthreads();

    float wq[8];
    #pragma unroll
    for (int nt = 0; nt < 8; ++nt)
        wq[nt] = wsq[nw * 128 + nt * 16 + lm];
    const int kbase = nw * 128 + lm;

    #pragma unroll
    for (int mt = 0; mt < 4; ++mt) {
        #pragma unroll
        for (int r = 0; r < 4; ++r) {
            float zz = zf[mt * 16 + lq * 4 + r];
            float q1 = INFINITY, q2 = INFINITY;
            int i1 = 0x7fffffff;
            #pragma unroll
            for (int nt = 0; nt < 8; ++nt) {
                float c2   = __fmul_rn(acc[mt][nt][r], 4.8828125e-4f);
                float dist = __fadd_rn(__fsub_rn(zz, c2), wq[nt]);
                int kk = kbase + nt * 16;
                if (dist < q1 || (dist == q1 && kk < i1)) { q2 = q1; q1 = dist; i1 = kk; }
                else if (dist < q2) q2 = dist;
            }
            #pragma unroll
            for (int mk = 1; mk <= 8; mk <<= 1) {
                float o1 = __shfl_xor(q1, mk);
                float o2 = __shfl_xor(q2, mk);
                int   oi = __shfl_xor(i1, mk);
                if (o1 < q1 || (o1 == q1 && oi < i1)) { q2 = fminf(q1, o2); q1 = o1; i1 = oi; }
                else { q2 = fminf(o1, q2); }
            }
            if (lm == 0) {
                int m = mt * 16 + lq * 4 + r;
                cb1[m * 4 + nw] = q1;
                cb2[m * 4 + nw] = q2;
                cbi[m * 4 + nw] = i1;
            }
        }
    }
    __syncthreads();
    if (tid < 64) {
        float q1 = cb1[tid * 4], q2 = cb2[tid * 4];
        int   i1 = cbi[tid * 4];
        #pragma unroll
        for (int p = 1; p < 4; ++p) {
            float c1 = cb1[tid * 4 + p], c2v = cb2[tid * 4 + p];
            int   ci = cbi[tid * 4 + p];
            if (c1 < q1 || (c1 == q1 && ci < i1)) { q2 = fminf(q1, c2v); q1 = c1; i1 = ci; }
            else { q2 = fminf(q2, c1); }
        }
        out[(size_t)b * NT + t0 + tid] = i1;
        if (q2 - q1 <= MARGIN) {
            int p = atomicAdd(&lcnt, 1);
            llist[p] = b * NT + t0 + tid;
        }
    }
    __syncthreads();
    if (tid == 0) gbase = (lcnt > 0) ? atomicAdd(gcnt, lcnt) : 0;
    __syncthreads();
    if (tid < lcnt) gties[gbase + tid] = llist[tid];
}

// ---------------------------------------------------------------------------
// Fallback (R1 kernel) if ws is too small.
// ---------------------------------------------------------------------------
#define BT 128
#define BK 128
#define DCHUNK 32
#define NKC (NK / BK)
#define NDC (DD / DCHUNK)
#define WSTR (BK + 4)

__global__ __launch_bounds__(256) void vq_fallback(const float* __restrict__ Z,
                                                   const float* __restrict__ W,
                                                   int* __restrict__ out) {
    __shared__ __align__(16) float Zs[DCHUNK * BT];
    __shared__ __align__(16) float Ws[DCHUNK * WSTR];
    __shared__ float wsqs[NK];

    const int tid = threadIdx.x;
    const int tx  = tid & 15;
    const int ty  = tid >> 4;
    const int b   = blockIdx.y;
    const int t0  = blockIdx.x * BT;

    for (int k = tid; k < NK; k += 256) {
        const float4* row = (const float4*)(W + (size_t)k * DD);
        double s = 0.0;
        for (int i = 0; i < DD / 4; ++i) {
            float4 v = row[i];
            s += (double)v.x * v.x + (double)v.y * v.y + (double)v.z * v.z + (double)v.w * v.w;
        }
        wsqs[k] = (float)s;
    }

    const float* Zb = Z + (size_t)b * DD * NT + t0;

    float best[8]; int bidx[8];
    #pragma unroll
    for (int a = 0; a < 8; ++a) { best[a] = INFINITY; bidx[a] = 0x7fffffff; }
    double zsqd[8];
    #pragma unroll
    for (int a = 0; a < 8; ++a) zsqd[a] = 0.0;
    float zsqf[8];

    for (int kc = 0; kc < NKC; ++kc) {
        float acc[8][8];
        #pragma unroll
        for (int a = 0; a < 8; ++a)
            #pragma unroll
            for (int c = 0; c < 8; ++c) acc[a][c] = 0.f;

        for (int dc = 0; dc < NDC; ++dc) {
            const int d0 = dc * DCHUNK;
            __syncthreads();
            #pragma unroll
            for (int i = 0; i < 4; ++i) {
                int f  = tid + i * 256;
                int r  = f >> 5;
                int c4 = f & 31;
                float4 v = *(const float4*)(Zb + (size_t)(d0 + r) * NT + c4 * 4);
                *(float4*)(&Zs[r * BT + c4 * 4]) = v;
            }
            #pragma unroll
            for (int i = 0; i < 4; ++i) {
                int u  = tid + i * 256;
                int k  = u >> 3;
                int rg = u & 7;
                float4 v = *(const float4*)(W + (size_t)(kc * BK + k) * DD + d0 + rg * 4);
                Ws[(rg * 4 + 0) * WSTR + k] = v.x;
                Ws[(rg * 4 + 1) * WSTR + k] = v.y;
                Ws[(rg * 4 + 2) * WSTR + k] = v.z;
                Ws[(rg * 4 + 3) * WSTR + k] = v.w;
            }
            __syncthreads();
            #pragma unroll 4
            for (int d = 0; d < DCHUNK; ++d) {
                float4 z0 = *(const float4*)(&Zs[d * BT + ty * 8]);
                float4 z1 = *(const float4*)(&Zs[d * BT + ty * 8 + 4]);
                float4 w0 = *(const float4*)(&Ws[d * WSTR + tx * 8]);
                float4 w1 = *(const float4*)(&Ws[d * WSTR + tx * 8 + 4]);
                float za[8] = {z0.x, z0.y, z0.z, z0.w, z1.x, z1.y, z1.z, z1.w};
                float wa[8] = {w0.x, w0.y, w0.z, w0.w, w1.x, w1.y, w1.z, w1.w};
                if (kc == 0) {
                    #pragma unroll
                    for (int a = 0; a < 8; ++a)
                        zsqd[a] = fma((double)za[a], (double)za[a], zsqd[a]);
                }
                #pragma unroll
                for (int a = 0; a < 8; ++a)
                    #pragma unroll
                    for (int c = 0; c < 8; ++c)
                        acc[a][c] = fmaf(za[a], wa[c], acc[a][c]);
            }
        }
        if (kc == 0) {
            #pragma unroll
            for (int a = 0; a < 8; ++a) zsqf[a] = (float)zsqd[a];
        }
        #pragma unroll
        for (int c = 0; c < 8; ++c) {
            int   kg = kc * BK + tx * 8 + c;
            float wqv = wsqs[kg];
            #pragma unroll
            for (int a = 0; a < 8; ++a) {
                float c2   = __fmul_rn(2.0f, acc[a][c]);
                float s    = __fsub_rn(zsqf[a], c2);
                float dist = __fadd_rn(s, wqv);
                if (dist < best[a] || (dist == best[a] && kg < bidx[a])) {
                    best[a] = dist; bidx[a] = kg;
                }
            }
        }
    }
    __syncthreads();
    float* redv = Zs;
    int*   redi = (int*)Ws;
    #pragma unroll
    for (int a = 0; a < 8; ++a) {
        int tl2 = ty * 8 + a;
        redv[tl2 * 16 + tx] = best[a];
        redi[tl2 * 16 + tx] = bidx[a];
    }
    __syncthreads();
    if (tid < BT) {
        float bv = INFINITY; int bi = 0x7fffffff;
        #pragma unroll
        for (int j = 0; j < 16; ++j) {
            float v = redv[tid * 16 + j];
            int   i = redi[tid * 16 + j];
            if (v < bv || (v == bv && i < bi)) { bv = v; bi = i; }
        }
        out[(size_t)b * NT + t0 + tid] = bi;
    }
}

extern "C" void kernel_launch(void* const* d_in, const int* in_sizes, int n_in,
                              void* d_out, int out_size, void* d_ws, size_t ws_size,
                              hipStream_t stream) {
    const float* Z = (const float*)d_in[0];   // [B, D, T]
    const float* W = (const float*)d_in[1];   // [K, D]
    int* out = (int*)d_out;                   // [B, T]

    // ---- tier-big layout (~70 MB, same footprint as the R4-validated run)
    const size_t OFF_WSQ  = 0;                         // 512 f32
    const size_t OFF_CNT  = 2048;                      // gcnt
    const size_t OFF_PCNT = 2052;                      // pcnt
    const size_t OFF_OFL  = 2056;                      // oflow
    const size_t OFF_ZQ   = 4096;                      // 131072 f32 (512 KB)
    const size_t OFF_WPP  = OFF_ZQ + 524288;           // 512 KB
    const size_t OFF_TIE  = OFF_WPP + 524288;          // 131072 ints
    const size_t OFF_SLOT = OFF_TIE + 524288;          // 131072 u64 (1 MB)
    const size_t OFF_PAIR = OFF_SLOT + 1048576;        // PCAP ints (2 MB)
    const size_t OFF_ZC   = OFF_PAIR + (size_t)PCAP * 4;          // ZCROWS KB
    const size_t NEED_BIG = OFF_ZC + (size_t)ZCROWS * 1024;       // ~69.6 MB

    // ---- tier-2 layout (R2 path)
    const size_t T2_WSQ = 0;
    const size_t T2_CNT = 2048;
    const size_t T2_WPP = 4096;
    const size_t T2_TIE = T2_WPP + 524288;
    const size_t NEED_T2 = T2_TIE + 524288;

    if (ws_size >= NEED_BIG) {
        float* wsq  = (float*)((char*)d_ws + OFF_WSQ);
        int*   gcnt = (int*)((char*)d_ws + OFF_CNT);
        int*   pcnt = (int*)((char*)d_ws + OFF_PCNT);
        int*   ofl  = (int*)((char*)d_ws + OFF_OFL);
        float* zq   = (float*)((char*)d_ws + OFF_ZQ);
        unsigned short* wpp = (unsigned short*)((char*)d_ws + OFF_WPP);
        int*   gties = (int*)((char*)d_ws + OFF_TIE);
        unsigned long long* slots = (unsigned long long*)((char*)d_ws + OFF_SLOT);
        int*   gpairs = (int*)((char*)d_ws + OFF_PAIR);
        float* zc   = (float*)((char*)d_ws + OFF_ZC);

        prep_kernel<<<dim3(NCH + 1), dim3(512), 0, stream>>>(W, wpp, wsq, gcnt, pcnt, ofl);
        vq_phase1<<<dim3(2048), dim3(256), 0, stream>>>(Z, wpp, wsq, out, gties, gcnt,
                                                        zc, zq, slots, gpairs, pcnt, ofl);
        vq_fix_pairs<<<dim3(512), dim3(256), 0, stream>>>(W, wsq, zc, zq, gpairs, pcnt, slots);
        vq_fix<<<dim3(256), dim3(256), 0, stream>>>(Z, W, wsq, gties, gcnt, out, ofl);
        vq_final<<<dim3(256), dim3(256), 0, stream>>>(gties, gcnt, ofl, slots, out);
    } else if (ws_size >= NEED_T2) {
        float* wsq  = (float*)((char*)d_ws + T2_WSQ);
        int*   gcnt = (int*)((char*)d_ws + T2_CNT);
        unsigned short* wpp = (unsigned short*)((char*)d_ws + T2_WPP);
        int*   gties = (int*)((char*)d_ws + T2_TIE);

        prep_kernel<<<dim3(NCH + 1), dim3(512), 0, stream>>>(W, wpp, wsq, gcnt, gcnt, gcnt);
        vq_phase1_reg<<<dim3(2048), dim3(256), 0, stream>>>(Z, wpp, wsq, out, gties, gcnt);
        vq_fix<<<dim3(256), dim3(256), 0, stream>>>(Z, W, wsq, gties, gcnt, out, nullptr);
    } else {
        vq_fallback<<<dim3(NT / BT, NB), dim3(256), 0, stream>>>(Z, W, out);
    }
}

// Round 10
// 338.376 us; speedup vs baseline: 1.1618x; 1.0606x over previous
//
#include <hip/hip_runtime.h>
#include <math.h>

#define NK 512
#define DD 256
#define NB 32
#define NT 4096

typedef __attribute__((ext_vector_type(8))) _Float16 f16x8;
typedef __attribute__((ext_vector_type(4))) float f32x4;

#define MARGIN 1.5e-4f
#define DCH 16      // d per chunk
#define NCH 16      // chunks (DD/DCH)
#define ASTR 536    // LDS row stride in shorts (1072 B: 268 dw, 268%32=12 -> 2-way max)
#define PCAP   524288      // global pair capacity
#define PBCAP  2048        // per-block pair list capacity (LDS overlay)
#define ZCROWS 65536       // Zc capacity (tokens); overflow -> guarded full fix

__device__ __forceinline__ unsigned short f16bits(float x) {
    _Float16 h = (_Float16)x;           // v_cvt_f16_f32, RNE
    unsigned short s;
    __builtin_memcpy(&s, &h, 2);
    return s;
}

// ---------------------------------------------------------------------------
// Prep W: blocks 0..15 build Wpp (f16 w*4096, duplicated per-d slot pair);
// block 16 computes wsq (fp64 -> fp32 once) and zeroes counters.
// ---------------------------------------------------------------------------
__global__ __launch_bounds__(512) void prep_kernel(const float* __restrict__ W,
                                                   unsigned short* __restrict__ Wpp,
                                                   float* __restrict__ wsq,
                                                   int* __restrict__ gcnt,
                                                   int* __restrict__ pcnt,
                                                   int* __restrict__ oflow) {
    const int bx = blockIdx.x;
    const int k  = threadIdx.x;   // 0..511
    if (bx < NCH) {
        const int d0 = bx * DCH;
        float w[16];
        const float4* src4 = (const float4*)(W + (size_t)k * DD + d0);
        #pragma unroll
        for (int q = 0; q < 4; ++q) {
            float4 v = src4[q];
            w[4 * q + 0] = v.x; w[4 * q + 1] = v.y; w[4 * q + 2] = v.z; w[4 * q + 3] = v.w;
        }
        __align__(16) unsigned int dw[16];
        #pragma unroll
        for (int j = 0; j < 16; ++j) {
            unsigned short s = f16bits(w[j] * 4096.0f);  // exact pow2 scale, then RNE
            dw[j] = (unsigned int)s | ((unsigned int)s << 16);  // (wh, wh) slot pair
        }
        unsigned short* dst = Wpp + ((size_t)bx * 512 + k) * 32;
        #pragma unroll
        for (int j = 0; j < 4; ++j) ((int4*)dst)[j] = ((const int4*)dw)[j];
    } else {
        const float4* row = (const float4*)(W + (size_t)k * DD);
        double s = 0.0;
        #pragma unroll 8
        for (int i = 0; i < DD / 4; ++i) {
            float4 v = row[i];
            s += (double)v.x * v.x + (double)v.y * v.y + (double)v.z * v.z + (double)v.w * v.w;
        }
        wsq[k] = (float)s;
        if (k == 0) *gcnt = 0;
        if (k == 1) *pcnt = 0;
        if (k == 2) *oflow = 0;
    }
}

// ---------------------------------------------------------------------------
// Phase 1 (big tier) = the R8-measured-best form EXACTLY (174 us): block =
// 64 t x 512 codes, 256 thr / 4 waves, acc[4][8], barrier-free K-loop, B
// depth-1 named dbuf from L2, light epilogue (top-2 merge -> out + gties +
// slots init + single-pass in-register candidate emit). NO Z gather here —
// that moved to vq_gather (wave-per-token). Approx-path numerics
// bit-identical to the validated kernel.
// ---------------------------------------------------------------------------
__global__ __launch_bounds__(256, 2) void vq_phase1(const float* __restrict__ Z,
                                                    const unsigned short* __restrict__ Wpp,
                                                    const float* __restrict__ wsq,
                                                    int* __restrict__ out,
                                                    int* __restrict__ gties,
                                                    int* __restrict__ gcnt,
                                                    unsigned long long* __restrict__ slots,
                                                    int* __restrict__ gpairs,
                                                    int* __restrict__ pcnt,
                                                    int* __restrict__ oflow) {
    __shared__ __align__(16) short As[64 * ASTR];   // 68,608 B
    __shared__ int lcnt, gbase, pcl, pbase_sh;

    const int tid  = threadIdx.x;
    const int wave = tid >> 6;
    const int lane = tid & 63;
    const int lm   = lane & 15;
    const int lq   = lane >> 4;
    const int nw   = wave;        // k quarter (128 codes)

    const int bx = blockIdx.x;
    const int b  = bx >> 6;
    const int t0 = (bx & 63) * 64;

    const int t_l = tid & 63;
    const int dgs = tid >> 6;     // 0..3, 64 d each

    const float* zcol = Z + (size_t)b * DD * NT + t0 + t_l;

    if (tid == 0) { lcnt = 0; pcl = 0; }

    // ---- staging: exact validated per-thread chain (64 loads, fp64, split)
    double zacc = 0.0;
    #pragma unroll
    for (int half = 0; half < 2; ++half) {
        float zv[32];
        #pragma unroll
        for (int j = 0; j < 32; ++j)
            zv[j] = zcol[(size_t)(dgs * 64 + half * 32 + j) * NT];
        #pragma unroll
        for (int j = 0; j < 32; ++j)
            zacc = fma((double)zv[j], (double)zv[j], zacc);
        #pragma unroll
        for (int j0 = 0; j0 < 32; j0 += 4) {
            __align__(16) unsigned int u[4];
            #pragma unroll
            for (int q = 0; q < 4; ++q) {
                float z = zv[j0 + q];
                _Float16 zh = (_Float16)z;
                float rz = z - (float)zh;     // exact (Sterbenz)
                unsigned short hs, ls;
                __builtin_memcpy(&hs, &zh, 2);
                ls = f16bits(rz);
                u[q] = (unsigned int)hs | ((unsigned int)ls << 16);  // (zh, zl)
            }
            *(int4*)&As[t_l * ASTR + (dgs * 64 + half * 32 + j0) * 2] = *(const int4*)u;
        }
    }
    __syncthreads();   // staging visible; the ONLY pre-epilogue barrier

    const unsigned short* wb = Wpp + ((size_t)(nw * 128 + lm) * 32) + lq * 8;

    f32x4 acc[4][8];
    #pragma unroll
    for (int mt = 0; mt < 4; ++mt)
        #pragma unroll
        for (int nt = 0; nt < 8; ++nt)
            acc[mt][nt] = (f32x4){0.f, 0.f, 0.f, 0.f};

    int4 bv0[8], bv1[8];
    #pragma unroll
    for (int nt = 0; nt < 8; ++nt)
        bv0[nt] = *(const int4*)(wb + nt * 512);

    #pragma unroll
    for (int c = 0; c < NCH; ++c) {
        int4* cur = (c & 1) ? bv1 : bv0;
        int4* nxt = (c & 1) ? bv0 : bv1;
        if (c < NCH - 1) {
            const unsigned short* wp = wb + (size_t)(c + 1) * 16384;
            #pragma unroll
            for (int nt = 0; nt < 8; ++nt)
                nxt[nt] = *(const int4*)(wp + nt * 512);
        }
        f16x8 a[4];
        #pragma unroll
        for (int mt = 0; mt < 4; ++mt)
            a[mt] = *(const f16x8*)&As[(mt * 16 + lm) * ASTR + c * 32 + lq * 8];
        #pragma unroll
        for (int mt = 0; mt < 4; ++mt)
            #pragma unroll
            for (int nt = 0; nt < 8; ++nt)
                acc[mt][nt] = __builtin_amdgcn_mfma_f32_16x16x32_f16(
                    a[mt], *(const f16x8*)&cur[nt], acc[mt][nt], 0, 0, 0);
    }

    // ---- epilogue. LDS overlay (As free after K-loop).
    __syncthreads();
    char* base = (char*)As;
    double* zred  = (double*)base;              // [4][64]  2048 B
    float*  zf    = (float*)(base + 2048);      // 64
    float*  qf    = (float*)(base + 2304);      // 64
    int*    tia   = (int*)(base + 2560);        // 64
    int*    ltok  = (int*)(base + 2816);        // 64
    float*  cb1   = (float*)(base + 3072);      // [64][4]
    float*  cb2   = (float*)(base + 4096);
    int*    cbi   = (int*)(base + 5120);
    int*    plist = (int*)(base + 6144);        // PBCAP ints (8 KB)

    zred[dgs * 64 + t_l] = zacc;
    __syncthreads();
    if (tid < 64) {
        double s = zred[tid];
        #pragma unroll
        for (int p = 1; p < 4; ++p) s += zred[p * 64 + tid];
        zf[tid] = (float)s;
    }
    __syncthreads();

    float wq[8];
    #pragma unroll
    for (int nt = 0; nt < 8; ++nt)
        wq[nt] = wsq[nw * 128 + nt * 16 + lm];
    const int kbase = nw * 128 + lm;

    #pragma unroll
    for (int mt = 0; mt < 4; ++mt) {
        #pragma unroll
        for (int r = 0; r < 4; ++r) {
            float zz = zf[mt * 16 + lq * 4 + r];
            float q1 = INFINITY, q2 = INFINITY;
            int i1 = 0x7fffffff;
            #pragma unroll
            for (int nt = 0; nt < 8; ++nt) {
                // acc holds cross*2^12; fl(2*cross) = acc * 2^-11 (exact pow2)
                float c2   = __fmul_rn(acc[mt][nt][r], 4.8828125e-4f);
                float dist = __fadd_rn(__fsub_rn(zz, c2), wq[nt]);
                int kk = kbase + nt * 16;
                if (dist < q1 || (dist == q1 && kk < i1)) { q2 = q1; q1 = dist; i1 = kk; }
                else if (dist < q2) q2 = dist;
            }
            #pragma unroll
            for (int mk = 1; mk <= 8; mk <<= 1) {
                float o1 = __shfl_xor(q1, mk);
                float o2 = __shfl_xor(q2, mk);
                int   oi = __shfl_xor(i1, mk);
                if (o1 < q1 || (o1 == q1 && oi < i1)) { q2 = fminf(q1, o2); q1 = o1; i1 = oi; }
                else { q2 = fminf(o1, q2); }
            }
            if (lm == 0) {
                int m = mt * 16 + lq * 4 + r;
                cb1[m * 4 + nw] = q1;
                cb2[m * 4 + nw] = q2;
                cbi[m * 4 + nw] = i1;
            }
        }
    }
    __syncthreads();
    if (tid < 64) {
        float q1 = cb1[tid * 4], q2 = cb2[tid * 4];
        int   i1 = cbi[tid * 4];
        #pragma unroll
        for (int p = 1; p < 4; ++p) {
            float c1 = cb1[tid * 4 + p], c2v = cb2[tid * 4 + p];
            int   ci = cbi[tid * 4 + p];
            if (c1 < q1 || (c1 == q1 && ci < i1)) { q2 = fminf(q1, c2v); q1 = c1; i1 = ci; }
            else { q2 = fminf(q2, c1); }
        }
        out[(size_t)b * NT + t0 + tid] = i1;
        qf[tid] = q1;
        int ta = -1;
        if (q2 - q1 <= MARGIN) {
            ta = atomicAdd(&lcnt, 1);
            ltok[ta] = tid;
        }
        tia[tid] = ta;
    }
    __syncthreads();           // merge done; lcnt/qf/tia final
    const int nloc = lcnt;
    if (nloc == 0) return;

    if (tid == 0) gbase = atomicAdd(gcnt, nloc);
    __syncthreads();

    // gties always written (backstop needs them); slots capacity == gcnt max
    if (tid < nloc) {
        gties[gbase + tid] = b * NT + t0 + ltok[tid];
        slots[gbase + tid] = 0xFFFFFFFFFFFFFFFFULL;
    }

    const bool okzc = (gbase + nloc <= ZCROWS);
    if (!okzc) {
        if (tid == 0) *oflow = 1;
        return;                 // full-fix backstop resolves everything
    }

    // ---- single-pass candidate emit: dists are live in registers
    #pragma unroll
    for (int mt = 0; mt < 4; ++mt) {
        #pragma unroll
        for (int r = 0; r < 4; ++r) {
            const int tok = mt * 16 + lq * 4 + r;
            const int ta  = tia[tok];
            if (ta < 0) continue;
            const int ti  = gbase + ta;
            const float thr = qf[tok] + MARGIN;
            const float zz  = zf[tok];
            #pragma unroll
            for (int nt = 0; nt < 8; ++nt) {
                float c2   = __fmul_rn(acc[mt][nt][r], 4.8828125e-4f);
                float dist = __fadd_rn(__fsub_rn(zz, c2), wq[nt]);
                if (dist <= thr) {
                    int p = atomicAdd(&pcl, 1);
                    if (p < PBCAP) plist[p] = (ti << 9) | (kbase + nt * 16);
                }
            }
        }
    }
    __syncthreads();
    if (tid == 0) {
        int take = pcl;
        int bs = atomicAdd(pcnt, take);
        pbase_sh = bs;
        if (take > PBCAP || bs + take > PCAP) *oflow = 1;
    }
    __syncthreads();
    {
        int take = pcl; if (take > PBCAP) take = PBCAP;
        for (int j = tid; j < take; j += 256) {
            int gp = pbase_sh + j;
            if (gp < PCAP) gpairs[gp] = plist[j];
        }
    }
}

// ---------------------------------------------------------------------------
// Gather (NEW): one WAVE per tie token. 64 lanes cooperatively load the Z
// column (4 strided loads/lane — 64x shorter latency chain than per-thread
// streaming), write Zc coalesced, and compute zq with the BIT-IDENTICAL
// validated chain: 32 seg partials (8-elem fp64 fma chains, ascending) then
// ordered left-fold sum over seg 0..31 by lane 0. Uniform trip count so
// block barriers are safe.
// ---------------------------------------------------------------------------
__global__ __launch_bounds__(256) void vq_gather(const float* __restrict__ Z,
                                                 const int* __restrict__ gties,
                                                 const int* __restrict__ gcnt,
                                                 const int* __restrict__ oflow,
                                                 float* __restrict__ Zc,
                                                 float* __restrict__ zq) {
    if (*oflow) return;
    const int n = *gcnt;
    if (n == 0) return;

    __shared__ float  col[4][256];
    __shared__ double pz[4][32];

    const int tid  = threadIdx.x;
    const int wv   = tid >> 6;
    const int lane = tid & 63;
    const int nwv  = (int)gridDim.x * 4;
    const int iters = (n + nwv - 1) / nwv;

    for (int it = 0; it < iters; ++it) {
        const int ti  = (blockIdx.x * 4 + wv) + it * nwv;
        const bool act = (ti < n);
        if (act) {
            const int bt = gties[ti];
            const int bb = bt >> 12, t = bt & 4095;
            const float* zp = Z + (size_t)bb * DD * NT + t;
            float v[4];
            #pragma unroll
            for (int j = 0; j < 4; ++j) {
                v[j] = zp[(size_t)(lane + 64 * j) * NT];
                col[wv][lane + 64 * j] = v[j];
            }
            #pragma unroll
            for (int j = 0; j < 4; ++j)
                Zc[(size_t)ti * 256 + lane + 64 * j] = v[j];
        }
        __syncthreads();
        if (act && lane < 32) {
            const float* cp = &col[wv][lane * 8];
            double s = 0.0;
            #pragma unroll
            for (int jj = 0; jj < 8; ++jj) {
                double zz = (double)cp[jj];
                s = fma(zz, zz, s);
            }
            pz[wv][lane] = s;
        }
        __syncthreads();
        if (act && lane == 0) {
            double tot = 0.0;
            #pragma unroll
            for (int sg = 0; sg < 32; ++sg) tot += pz[wv][sg];
            zq[ti] = (float)tot;
        }
        __syncthreads();
    }
}

// ---------------------------------------------------------------------------
// Pair fix (R4/R9-validated): one thread per (tie-token, candidate-code)
// pair; exact fp32 fmaf chain over the COMPACT coalesced Zc row +
// precomputed zq. Winner per token via 64-bit atomicMin on
// (dist_bits<<32 | k) — the validated comparator.
// ---------------------------------------------------------------------------
__global__ __launch_bounds__(256) void vq_fix_pairs(const float* __restrict__ W,
                                                    const float* __restrict__ wsq,
                                                    const float* __restrict__ Zc,
                                                    const float* __restrict__ zq,
                                                    const int* __restrict__ gpairs,
                                                    const int* __restrict__ pcnt,
                                                    const int* __restrict__ oflow,
                                                    unsigned long long* __restrict__ slots) {
    if (*oflow) return;
    int np = *pcnt;
    if (np > PCAP) np = PCAP;
    for (int j = blockIdx.x * 256 + threadIdx.x; j < np; j += (int)gridDim.x * 256) {
        const int p  = gpairs[j];
        const int ti = p >> 9;
        const int k  = p & 511;
        if (ti >= ZCROWS) continue;
        const float4* zr = (const float4*)(Zc + (size_t)ti * 256);
        const float4* wr = (const float4*)(W + (size_t)k * DD);
        float a8 = 0.f;
        #pragma unroll 4
        for (int q = 0; q < 64; ++q) {
            float4 w4 = wr[q];
            float4 z4 = zr[q];
            a8 = fmaf(z4.x, w4.x, a8);
            a8 = fmaf(z4.y, w4.y, a8);
            a8 = fmaf(z4.z, w4.z, a8);
            a8 = fmaf(z4.w, w4.w, a8);
        }
        float da = __fadd_rn(__fsub_rn(zq[ti], __fmul_rn(2.0f, a8)), wsq[k]);
        unsigned long long key =
            ((unsigned long long)__float_as_uint(da) << 32) | (unsigned int)k;
        atomicMin(&slots[ti], key);
    }
}

// ---------------------------------------------------------------------------
// Final readout (skipped on overflow): out[bt] = winning k from slots.
// ---------------------------------------------------------------------------
__global__ __launch_bounds__(256) void vq_final(const int* __restrict__ gties,
                                                const int* __restrict__ gcnt,
                                                const int* __restrict__ oflow,
                                                const unsigned long long* __restrict__ slots,
                                                int* __restrict__ out) {
    if (*oflow) return;
    const int n = *gcnt;
    for (int j = blockIdx.x * 256 + threadIdx.x; j < n; j += (int)gridDim.x * 256) {
        out[gties[j]] = (int)(slots[j] & 511ULL);
    }
}

// ---------------------------------------------------------------------------
// Full tie fix (R2-validated). Big tier: runs only on overflow (oflow!=0).
// Tier-2: oflow == nullptr -> always runs.
// ---------------------------------------------------------------------------
__global__ __launch_bounds__(256) void vq_fix(const float* __restrict__ Z,
                                              const float* __restrict__ W,
                                              const float* __restrict__ wsq,
                                              const int* __restrict__ gties,
                                              const int* __restrict__ gcnt,
                                              int* __restrict__ out,
                                              const int* __restrict__ oflow) {
    if (oflow != nullptr && *oflow == 0) return;

    __shared__ __align__(16) float Zs[8][256];
    __shared__ double pz[8][32];
    __shared__ float  zsqs[8];
    __shared__ int    bts[8];
    __shared__ float  rv[8][4];
    __shared__ int    ri[8][4];

    const int tid  = threadIdx.x;
    const int lane = tid & 63;
    const int wvx  = tid >> 6;
    const int n    = *gcnt;

    for (int base = blockIdx.x * 8; base < n; base += (int)gridDim.x * 8) {
        const int m = (n - base < 8) ? (n - base) : 8;
        __syncthreads();
        if (tid < 8) bts[tid] = gties[base + ((tid < m) ? tid : 0)];
        __syncthreads();

        #pragma unroll
        for (int i = 0; i < 8; ++i) {
            if (i < m) {
                int tb = bts[i];
                int bb = tb >> 12, t = tb & 4095;
                Zs[i][tid] = Z[(size_t)bb * DD * NT + (size_t)tid * NT + t];
            }
        }
        __syncthreads();

        {
            int i = tid >> 5, seg = tid & 31;
            double s = 0.0;
            #pragma unroll
            for (int j = 0; j < 8; ++j) {
                double zz = (double)Zs[i][seg * 8 + j];
                s = fma(zz, zz, s);
            }
            pz[i][seg] = s;
        }
        __syncthreads();
        if (tid < 8) {
            double s = 0.0;
            #pragma unroll
            for (int j = 0; j < 32; ++j) s += pz[tid][j];
            zsqs[tid] = (float)s;
        }
        __syncthreads();

        float da[2][8];
        #pragma unroll
        for (int rr = 0; rr < 2; ++rr) {
            int k = tid + rr * 256;
            const float4* wr = (const float4*)(W + (size_t)k * DD);
            float a8[8];
            #pragma unroll
            for (int i = 0; i < 8; ++i) a8[i] = 0.f;
            #pragma unroll 2
            for (int q = 0; q < 64; ++q) {
                float4 w4 = wr[q];
                #pragma unroll
                for (int i = 0; i < 8; ++i) {
                    float4 z4 = *(const float4*)&Zs[i][4 * q];   // LDS broadcast
                    a8[i] = fmaf(z4.x, w4.x, a8[i]);
                    a8[i] = fmaf(z4.y, w4.y, a8[i]);
                    a8[i] = fmaf(z4.z, w4.z, a8[i]);
                    a8[i] = fmaf(z4.w, w4.w, a8[i]);
                }
            }
            float wqv = wsq[k];
            #pragma unroll
            for (int i = 0; i < 8; ++i)
                da[rr][i] = __fadd_rn(__fsub_rn(zsqs[i], __fmul_rn(2.0f, a8[i])), wqv);
        }

        #pragma unroll
        for (int i = 0; i < 8; ++i) {
            float v = da[0][i]; int ix = tid;
            if (da[1][i] < v) { v = da[1][i]; ix = tid + 256; }
            #pragma unroll
            for (int mk = 1; mk <= 32; mk <<= 1) {
                float ov = __shfl_xor(v, mk);
                int   oi = __shfl_xor(ix, mk);
                if (ov < v || (ov == v && oi < ix)) { v = ov; ix = oi; }
            }
            if (lane == 0) { rv[i][wvx] = v; ri[i][wvx] = ix; }
        }
        __syncthreads();
        if (tid < 8 && tid < m) {
            float v = INFINITY; int ix = 0x7fffffff;
            #pragma unroll
            for (int w = 0; w < 4; ++w) {
                if (rv[tid][w] < v || (rv[tid][w] == v && ri[tid][w] < ix)) {
                    v = rv[tid][w]; ix = ri[tid][w];
                }
            }
            out[bts[tid]] = ix;
        }
    }
}

// ---------------------------------------------------------------------------
// Phase 1 (tier-2, R2-validated): 4-wave, in-kernel staging.
// ---------------------------------------------------------------------------
__global__ __launch_bounds__(256, 2) void vq_phase1_reg(const float* __restrict__ Z,
                                                        const unsigned short* __restrict__ Wpp,
                                                        const float* __restrict__ wsq,
                                                        int* __restrict__ out,
                                                        int* __restrict__ gties,
                                                        int* __restrict__ gcnt) {
    __shared__ __align__(16) short As[64 * ASTR];
    __shared__ int lcnt, gbase;

    const int tid  = threadIdx.x;
    const int wave = tid >> 6;
    const int lane = tid & 63;
    const int lm   = lane & 15;
    const int lq   = lane >> 4;
    const int nw   = wave;

    const int bx = blockIdx.x;
    const int b  = bx >> 6;
    const int t0 = (bx & 63) * 64;

    const int t_l = tid & 63;
    const int dgs = tid >> 6;

    const float* zcol = Z + (size_t)b * DD * NT + t0 + t_l;

    if (tid == 0) lcnt = 0;

    double zacc = 0.0;
    #pragma unroll
    for (int half = 0; half < 2; ++half) {
        float zv[32];
        #pragma unroll
        for (int j = 0; j < 32; ++j)
            zv[j] = zcol[(size_t)(dgs * 64 + half * 32 + j) * NT];
        #pragma unroll
        for (int j = 0; j < 32; ++j)
            zacc = fma((double)zv[j], (double)zv[j], zacc);
        #pragma unroll
        for (int j0 = 0; j0 < 32; j0 += 4) {
            __align__(16) unsigned int u[4];
            #pragma unroll
            for (int q = 0; q < 4; ++q) {
                float z = zv[j0 + q];
                _Float16 zh = (_Float16)z;
                float rz = z - (float)zh;
                unsigned short hs, ls;
                __builtin_memcpy(&hs, &zh, 2);
                ls = f16bits(rz);
                u[q] = (unsigned int)hs | ((unsigned int)ls << 16);
            }
            *(int4*)&As[t_l * ASTR + (dgs * 64 + half * 32 + j0) * 2] = *(const int4*)u;
        }
    }
    __syncthreads();

    const unsigned short* wb = Wpp + ((size_t)(nw * 128 + lm) * 32) + lq * 8;

    f32x4 acc[4][8];
    #pragma unroll
    for (int mt = 0; mt < 4; ++mt)
        #pragma unroll
        for (int nt = 0; nt < 8; ++nt)
            acc[mt][nt] = (f32x4){0.f, 0.f, 0.f, 0.f};

    int4 bv0[8], bv1[8];
    #pragma unroll
    for (int nt = 0; nt < 8; ++nt)
        bv0[nt] = *(const int4*)(wb + nt * 512);

    #pragma unroll
    for (int c = 0; c < NCH; ++c) {
        int4* cur = (c & 1) ? bv1 : bv0;
        int4* nxt = (c & 1) ? bv0 : bv1;
        if (c < NCH - 1) {
            const unsigned short* wp = wb + (size_t)(c + 1) * 16384;
            #pragma unroll
            for (int nt = 0; nt < 8; ++nt)
                nxt[nt] = *(const int4*)(wp + nt * 512);
        }
        f16x8 a[4];
        #pragma unroll
        for (int mt = 0; mt < 4; ++mt)
            a[mt] = *(const f16x8*)&As[(mt * 16 + lm) * ASTR + c * 32 + lq * 8];
        #pragma unroll
        for (int mt = 0; mt < 4; ++mt)
            #pragma unroll
            for (int nt = 0; nt < 8; ++nt)
                acc[mt][nt] = __builtin_amdgcn_mfma_f32_16x16x32_f16(
                    a[mt], *(const f16x8*)&cur[nt], acc[mt][nt], 0, 0, 0);
    }

    __syncthreads();
    double* zred = (double*)As;
    float*  zf   = (float*)(As + 1024);
    float*  cb1  = (float*)(As + 1536);
    float*  cb2  = (float*)(As + 2048);
    int*    cbi  = (int*)(As + 2560);
    int*    llist = (int*)(As + 3072);

    zred[dgs * 64 + t_l] = zacc;
    __syncthreads();
    if (tid < 64) {
        double s = zred[tid];
        #pragma unroll
        for (int p = 1; p < 4; ++p) s += zred[p * 64 + tid];
        zf[tid] = (float)s;
    }
    __syncthreads();

    float wq[8];
    #pragma unroll
    for (int nt = 0; nt < 8; ++nt)
        wq[nt] = wsq[nw * 128 + nt * 16 + lm];
    const int kbase = nw * 128 + lm;

    #pragma unroll
    for (int mt = 0; mt < 4; ++mt) {
        #pragma unroll
        for (int r = 0; r < 4; ++r) {
            float zz = zf[mt * 16 + lq * 4 + r];
            float q1 = INFINITY, q2 = INFINITY;
            int i1 = 0x7fffffff;
            #pragma unroll
            for (int nt = 0; nt < 8; ++nt) {
                float c2   = __fmul_rn(acc[mt][nt][r], 4.8828125e-4f);
                float dist = __fadd_rn(__fsub_rn(zz, c2), wq[nt]);
                int kk = kbase + nt * 16;
                if (dist < q1 || (dist == q1 && kk < i1)) { q2 = q1; q1 = dist; i1 = kk; }
                else if (dist < q2) q2 = dist;
            }
            #pragma unroll
            for (int mk = 1; mk <= 8; mk <<= 1) {
                float o1 = __shfl_xor(q1, mk);
                float o2 = __shfl_xor(q2, mk);
                int   oi = __shfl_xor(i1, mk);
                if (o1 < q1 || (o1 == q1 && oi < i1)) { q2 = fminf(q1, o2); q1 = o1; i1 = oi; }
                else { q2 = fminf(o1, q2); }
            }
            if (lm == 0) {
                int m = mt * 16 + lq * 4 + r;
                cb1[m * 4 + nw] = q1;
                cb2[m * 4 + nw] = q2;
                cbi[m * 4 + nw] = i1;
            }
        }
    }
    __syncthreads();
    if (tid < 64) {
        float q1 = cb1[tid * 4], q2 = cb2[tid * 4];
        int   i1 = cbi[tid * 4];
        #pragma unroll
        for (int p = 1; p < 4; ++p) {
            float c1 = cb1[tid * 4 + p], c2v = cb2[tid * 4 + p];
            int   ci = cbi[tid * 4 + p];
            if (c1 < q1 || (c1 == q1 && ci < i1)) { q2 = fminf(q1, c2v); q1 = c1; i1 = ci; }
            else { q2 = fminf(q2, c1); }
        }
        out[(size_t)b * NT + t0 + tid] = i1;
        if (q2 - q1 <= MARGIN) {
            int p = atomicAdd(&lcnt, 1);
            llist[p] = b * NT + t0 + tid;
        }
    }
    __syncthreads();
    if (tid == 0) gbase = (lcnt > 0) ? atomicAdd(gcnt, lcnt) : 0;
    __syncthreads();
    if (tid < lcnt) gties[gbase + tid] = llist[tid];
}

// ---------------------------------------------------------------------------
// Fallback (R1 kernel) if ws is too small.
// ---------------------------------------------------------------------------
#define BT 128
#define BK 128
#define DCHUNK 32
#define NKC (NK / BK)
#define NDC (DD / DCHUNK)
#define WSTR (BK + 4)

__global__ __launch_bounds__(256) void vq_fallback(const float* __restrict__ Z,
                                                   const float* __restrict__ W,
                                                   int* __restrict__ out) {
    __shared__ __align__(16) float Zs[DCHUNK * BT];
    __shared__ __align__(16) float Ws[DCHUNK * WSTR];
    __shared__ float wsqs[NK];

    const int tid = threadIdx.x;
    const int tx  = tid & 15;
    const int ty  = tid >> 4;
    const int b   = blockIdx.y;
    const int t0  = blockIdx.x * BT;

    for (int k = tid; k < NK; k += 256) {
        const float4* row = (const float4*)(W + (size_t)k * DD);
        double s = 0.0;
        for (int i = 0; i < DD / 4; ++i) {
            float4 v = row[i];
            s += (double)v.x * v.x + (double)v.y * v.y + (double)v.z * v.z + (double)v.w * v.w;
        }
        wsqs[k] = (float)s;
    }

    const float* Zb = Z + (size_t)b * DD * NT + t0;

    float best[8]; int bidx[8];
    #pragma unroll
    for (int a = 0; a < 8; ++a) { best[a] = INFINITY; bidx[a] = 0x7fffffff; }
    double zsqd[8];
    #pragma unroll
    for (int a = 0; a < 8; ++a) zsqd[a] = 0.0;
    float zsqf[8];

    for (int kc = 0; kc < NKC; ++kc) {
        float acc[8][8];
        #pragma unroll
        for (int a = 0; a < 8; ++a)
            #pragma unroll
            for (int c = 0; c < 8; ++c) acc[a][c] = 0.f;

        for (int dc = 0; dc < NDC; ++dc) {
            const int d0 = dc * DCHUNK;
            __syncthreads();
            #pragma unroll
            for (int i = 0; i < 4; ++i) {
                int f  = tid + i * 256;
                int r  = f >> 5;
                int c4 = f & 31;
                float4 v = *(const float4*)(Zb + (size_t)(d0 + r) * NT + c4 * 4);
                *(float4*)(&Zs[r * BT + c4 * 4]) = v;
            }
            #pragma unroll
            for (int i = 0; i < 4; ++i) {
                int u  = tid + i * 256;
                int k  = u >> 3;
                int rg = u & 7;
                float4 v = *(const float4*)(W + (size_t)(kc * BK + k) * DD + d0 + rg * 4);
                Ws[(rg * 4 + 0) * WSTR + k] = v.x;
                Ws[(rg * 4 + 1) * WSTR + k] = v.y;
                Ws[(rg * 4 + 2) * WSTR + k] = v.z;
                Ws[(rg * 4 + 3) * WSTR + k] = v.w;
            }
            __syncthreads();
            #pragma unroll 4
            for (int d = 0; d < DCHUNK; ++d) {
                float4 z0 = *(const float4*)(&Zs[d * BT + ty * 8]);
                float4 z1 = *(const float4*)(&Zs[d * BT + ty * 8 + 4]);
                float4 w0 = *(const float4*)(&Ws[d * WSTR + tx * 8]);
                float4 w1 = *(const float4*)(&Ws[d * WSTR + tx * 8 + 4]);
                float za[8] = {z0.x, z0.y, z0.z, z0.w, z1.x, z1.y, z1.z, z1.w};
                float wa[8] = {w0.x, w0.y, w0.z, w0.w, w1.x, w1.y, w1.z, w1.w};
                if (kc == 0) {
                    #pragma unroll
                    for (int a = 0; a < 8; ++a)
                        zsqd[a] = fma((double)za[a], (double)za[a], zsqd[a]);
                }
                #pragma unroll
                for (int a = 0; a < 8; ++a)
                    #pragma unroll
                    for (int c = 0; c < 8; ++c)
                        acc[a][c] = fmaf(za[a], wa[c], acc[a][c]);
            }
        }
        if (kc == 0) {
            #pragma unroll
            for (int a = 0; a < 8; ++a) zsqf[a] = (float)zsqd[a];
        }
        #pragma unroll
        for (int c = 0; c < 8; ++c) {
            int   kg = kc * BK + tx * 8 + c;
            float wqv = wsqs[kg];
            #pragma unroll
            for (int a = 0; a < 8; ++a) {
                float c2   = __fmul_rn(2.0f, acc[a][c]);
                float s    = __fsub_rn(zsqf[a], c2);
                float dist = __fadd_rn(s, wqv);
                if (dist < best[a] || (dist == best[a] && kg < bidx[a])) {
                    best[a] = dist; bidx[a] = kg;
                }
            }
        }
    }
    __syncthreads();
    float* redv = Zs;
    int*   redi = (int*)Ws;
    #pragma unroll
    for (int a = 0; a < 8; ++a) {
        int tl2 = ty * 8 + a;
        redv[tl2 * 16 + tx] = best[a];
        redi[tl2 * 16 + tx] = bidx[a];
    }
    __syncthreads();
    if (tid < BT) {
        float bv = INFINITY; int bi = 0x7fffffff;
        #pragma unroll
        for (int j = 0; j < 16; ++j) {
            float v = redv[tid * 16 + j];
            int   i = redi[tid * 16 + j];
            if (v < bv || (v == bv && i < bi)) { bv = v; bi = i; }
        }
        out[(size_t)b * NT + t0 + tid] = bi;
    }
}

extern "C" void kernel_launch(void* const* d_in, const int* in_sizes, int n_in,
                              void* d_out, int out_size, void* d_ws, size_t ws_size,
                              hipStream_t stream) {
    const float* Z = (const float*)d_in[0];   // [B, D, T]
    const float* W = (const float*)d_in[1];   // [K, D]
    int* out = (int*)d_out;                   // [B, T]

    // ---- tier-big layout (~70 MB)
    const size_t OFF_WSQ  = 0;                         // 512 f32
    const size_t OFF_CNT  = 2048;                      // gcnt
    const size_t OFF_PCNT = 2052;                      // pcnt
    const size_t OFF_OFL  = 2056;                      // oflow
    const size_t OFF_ZQ   = 4096;                      // 131072 f32 (512 KB)
    const size_t OFF_WPP  = OFF_ZQ + 524288;           // 512 KB
    const size_t OFF_TIE  = OFF_WPP + 524288;          // 131072 ints
    const size_t OFF_SLOT = OFF_TIE + 524288;          // 131072 u64 (1 MB)
    const size_t OFF_PAIR = OFF_SLOT + 1048576;        // PCAP ints (2 MB)
    const size_t OFF_ZC   = OFF_PAIR + (size_t)PCAP * 4;          // ZCROWS KB
    const size_t NEED_BIG = OFF_ZC + (size_t)ZCROWS * 1024;       // ~69.6 MB

    // ---- tier-2 layout (R2 path)
    const size_t T2_WSQ = 0;
    const size_t T2_CNT = 2048;
    const size_t T2_WPP = 4096;
    const size_t T2_TIE = T2_WPP + 524288;
    const size_t NEED_T2 = T2_TIE + 524288;

    if (ws_size >= NEED_BIG) {
        float* wsq  = (float*)((char*)d_ws + OFF_WSQ);
        int*   gcnt = (int*)((char*)d_ws + OFF_CNT);
        int*   pcnt = (int*)((char*)d_ws + OFF_PCNT);
        int*   ofl  = (int*)((char*)d_ws + OFF_OFL);
        float* zq   = (float*)((char*)d_ws + OFF_ZQ);
        unsigned short* wpp = (unsigned short*)((char*)d_ws + OFF_WPP);
        int*   gties = (int*)((char*)d_ws + OFF_TIE);
        unsigned long long* slots = (unsigned long long*)((char*)d_ws + OFF_SLOT);
        int*   gpairs = (int*)((char*)d_ws + OFF_PAIR);
        float* zc   = (float*)((char*)d_ws + OFF_ZC);

        prep_kernel<<<dim3(NCH + 1), dim3(512), 0, stream>>>(W, wpp, wsq, gcnt, pcnt, ofl);
        vq_phase1<<<dim3(2048), dim3(256), 0, stream>>>(Z, wpp, wsq, out, gties, gcnt,
                                                        slots, gpairs, pcnt, ofl);
        vq_gather<<<dim3(512), dim3(256), 0, stream>>>(Z, gties, gcnt, ofl, zc, zq);
        vq_fix_pairs<<<dim3(512), dim3(256), 0, stream>>>(W, wsq, zc, zq, gpairs, pcnt, ofl, slots);
        vq_fix<<<dim3(256), dim3(256), 0, stream>>>(Z, W, wsq, gties, gcnt, out, ofl);
        vq_final<<<dim3(256), dim3(256), 0, stream>>>(gties, gcnt, ofl, slots, out);
    } else if (ws_size >= NEED_T2) {
        float* wsq  = (float*)((char*)d_ws + T2_WSQ);
        int*   gcnt = (int*)((char*)d_ws + T2_CNT);
        unsigned short* wpp = (unsigned short*)((char*)d_ws + T2_WPP);
        int*   gties = (int*)((char*)d_ws + T2_TIE);

        prep_kernel<<<dim3(NCH + 1), dim3(512), 0, stream>>>(W, wpp, wsq, gcnt, gcnt, gcnt);
        vq_phase1_reg<<<dim3(2048), dim3(256), 0, stream>>>(Z, wpp, wsq, out, gties, gcnt);
        vq_fix<<<dim3(256), dim3(256), 0, stream>>>(Z, W, wsq, gties, gcnt, out, nullptr);
    } else {
        vq_fallback<<<dim3(NT / BT, NB), dim3(256), 0, stream>>>(Z, W, out);
    }
}